// Round 10
// baseline (22260.957 us; speedup 1.0000x reference)
//
#include <hip/hip_runtime.h>

#define T_SEQ 200
#define NB    32
#define NE    300
#define NH    1000
#define NK    9
#define NJ    4096          // xg rows per t
#define EPD   320           // padded embed K
#define WSCALE 256.0f
#define HSCALE 16.0f
#define LSCALE 512.0f
#define GSCALE (1.0f / (256.0f * 16.0f))
#define TSCALE (1.0f / (16.0f * 512.0f))

typedef __attribute__((ext_vector_type(4))) float f32x4;
typedef __attribute__((ext_vector_type(8))) short s16x8;
typedef __attribute__((ext_vector_type(4))) short s16x4;
typedef unsigned long long u64;

__device__ __forceinline__ unsigned short f2bf(float f) {
    union { float f; unsigned u; } v; v.f = f;
    unsigned r = v.u + 0x7FFFu + ((v.u >> 16) & 1u);   // RNE
    return (unsigned short)(r >> 16);
}
__device__ __forceinline__ float bf2f(unsigned short h) {
    union { unsigned u; float f; } v; v.u = ((unsigned)h) << 16;
    return v.f;
}
__device__ __forceinline__ float ftanh(float x) {
    float e = __expf(fminf(2.f * x, 80.f));
    return (e - 1.f) / (e + 1.f);
}
__device__ __forceinline__ float fsig(float x) {
    return 1.f / (1.f + __expf(-x));
}
// L1-bypass, L2-served load (intra-XCD coherent poll)
__device__ __forceinline__ unsigned poll_sc0(const unsigned* p) {
    unsigned r;
    asm volatile("global_load_dword %0, %1, off sc0\n\t"
                 "s_waitcnt vmcnt(0)"
                 : "=v"(r) : "v"(p) : "memory");
    return r;
}

// ---------------------------------------------------------------------------
// prep_emb: gather+convert embeds -> bf16; block 0 inits ctrl block
// ctrl[0..31]=step flags, ctrl[40..55]=per-XCD tickets, ctrl[60]=arrivals,
// ctrl[61]=winner (0xffffffff sentinel)
// ---------------------------------------------------------------------------
__global__ __launch_bounds__(256) void prep_emb(
    const int* __restrict__ x, const float* __restrict__ embed_w,
    unsigned short* __restrict__ emb_bf, unsigned* __restrict__ ctrl)
{
    const int t = blockIdx.x, tid = threadIdx.x;
    if (blockIdx.x == 0) {
        for (int i = tid; i < 2048; i += 256)
            ctrl[i] = (i == 61) ? 0xffffffffu : 0u;
    }
    for (int idx = tid; idx < NB * EPD; idx += 256) {
        int b = idx / EPD, e = idx - b * EPD;
        float v = (e < NE) ? embed_w[(size_t)x[t * NB + b] * NE + e] : 0.f;
        emb_bf[((size_t)t * NB + b) * EPD + e] = f2bf(v);
    }
}

// ---------------------------------------------------------------------------
// prep_w: W_ih -> bf16 [jp][320]; blocks 0..15 also quantize lin_w row n=blk
// to fp8 x512 into linw_q[16][1024]
// ---------------------------------------------------------------------------
__global__ __launch_bounds__(256) void prep_w(
    const float* __restrict__ W_ih, const float* __restrict__ b_ih,
    const float* __restrict__ b_hh, const float* __restrict__ lin_w,
    unsigned short* __restrict__ wih_bf, float* __restrict__ biasg,
    unsigned char* __restrict__ linw_q)
{
    const int blk = blockIdx.x, tid = threadIdx.x;
    for (int idx = tid; idx < 64 * EPD; idx += 256) {
        int jr = idx / EPD, e = idx - jr * EPD;
        int jp = blk * 64 + jr;
        int wgu = jp >> 7, rr = jp & 127, g = rr >> 5, uu = rr & 31;
        int m = wgu * 32 + uu;
        float v = (m < NH && e < NE) ? W_ih[(size_t)(g * NH + m) * NE + e] : 0.f;
        wih_bf[(size_t)jp * EPD + e] = f2bf(v);
    }
    if (tid < 64) {
        int jp = blk * 64 + tid;
        int wgu = jp >> 7, rr = jp & 127, g = rr >> 5, uu = rr & 31;
        int m = wgu * 32 + uu;
        biasg[jp] = (m < NH) ? (b_ih[g * NH + m] + b_hh[g * NH + m]) : 0.f;
    }
    if (blk < 16) {
        int n = blk, k = tid * 4;
        float v0 = (n < NK && k + 0 < NH) ? lin_w[(size_t)n * NH + k + 0] * LSCALE : 0.f;
        float v1 = (n < NK && k + 1 < NH) ? lin_w[(size_t)n * NH + k + 1] * LSCALE : 0.f;
        float v2 = (n < NK && k + 2 < NH) ? lin_w[(size_t)n * NH + k + 2] * LSCALE : 0.f;
        float v3 = (n < NK && k + 3 < NH) ? lin_w[(size_t)n * NH + k + 3] * LSCALE : 0.f;
        int p01 = __builtin_amdgcn_cvt_pk_fp8_f32(v0, v1, 0, false);
        int p23 = __builtin_amdgcn_cvt_pk_fp8_f32(v2, v3, 0, false);
        ((unsigned*)linw_q)[n * 256 + tid] =
            ((unsigned)p01 & 0xffffu) | ((unsigned)p23 << 16);
    }
}

// ---------------------------------------------------------------------------
__global__ __launch_bounds__(256) void proj_kernel(
    const unsigned short* __restrict__ emb_bf,
    const unsigned short* __restrict__ wih_bf,
    const float* __restrict__ biasg, unsigned short* __restrict__ xg)
{
    const int jt = blockIdx.x, t = blockIdx.y, tid = threadIdx.x;
    const int w = tid >> 6, lane = tid & 63;
    const int col = lane & 15, quad = lane >> 4;

    const unsigned short* eb = emb_bf + (size_t)t * NB * EPD;
    const unsigned short* wb = wih_bf + (size_t)(jt * 64 + w * 16 + col) * EPD;
    const unsigned short* ea0 = eb + (size_t)col * EPD;
    const unsigned short* ea1 = eb + (size_t)(16 + col) * EPD;

    f32x4 acc0 = {0.f, 0.f, 0.f, 0.f};
    f32x4 acc1 = {0.f, 0.f, 0.f, 0.f};
#pragma unroll
    for (int kc = 0; kc < EPD / 32; ++kc) {
        int ko = kc * 32 + quad * 8;
        s16x8 a0 = *(const s16x8*)&ea0[ko];
        s16x8 a1 = *(const s16x8*)&ea1[ko];
        s16x8 bb = *(const s16x8*)&wb[ko];
        acc0 = __builtin_amdgcn_mfma_f32_16x16x32_bf16(a0, bb, acc0, 0, 0, 0);
        acc1 = __builtin_amdgcn_mfma_f32_16x16x32_bf16(a1, bb, acc1, 0, 0, 0);
    }
    const int jp = jt * 64 + w * 16 + col;
    const float bi = biasg[jp];
    size_t base = ((size_t)t * NJ + jp) * NB;
    s16x4 p0, p1;
#pragma unroll
    for (int r = 0; r < 4; ++r) {
        p0[r] = (short)f2bf(acc0[r] + bi);
        p1[r] = (short)f2bf(acc1[r] + bi);
    }
    *(s16x4*)&xg[base + quad * 4]      = p0;
    *(s16x4*)&xg[base + 16 + quad * 4] = p1;
}

// ---------------------------------------------------------------------------
// lstm: grid 256, 1 WG/CU => 32 co-resident per XCD; election picks one XCD.
// h exchange AND flags both via the shared per-XCD L2: plain write-through
// stores; consumers use sc0 loads (L1 bypass) for the reused flag addresses,
// plain loads for the fresh-per-step h pages. No HBM stores in the loop.
// Fallback: every 1024th spin uses an agent(MALL) load — can't hang.
// ---------------------------------------------------------------------------
__global__ __launch_bounds__(256, 1) void lstm_kernel(
    const float* __restrict__ W_hh,
    const unsigned short* __restrict__ xg,
    unsigned char* __restrict__ h_q,
    unsigned* __restrict__ ctrl)
{
    __shared__ __align__(16) unsigned char s_w[128 * 1024];   // 131,072 B
    __shared__ __align__(4) unsigned char s_pack[1024];       // [b(32)][u(32)]
    __shared__ int s_chunk;

    const int tid = threadIdx.x;

    // ---- election (startup only, MALL atomics) ----
    if (tid == 0) {
        unsigned xcc;
        asm volatile("s_getreg_b32 %0, hwreg(HW_REG_XCC_ID)" : "=s"(xcc));
        xcc &= 15u;
        unsigned myidx = __hip_atomic_fetch_add(&ctrl[40 + xcc], 1u,
                             __ATOMIC_RELAXED, __HIP_MEMORY_SCOPE_AGENT);
        __threadfence();
        unsigned tot = __hip_atomic_fetch_add(&ctrl[60], 1u,
                             __ATOMIC_RELAXED, __HIP_MEMORY_SCOPE_AGENT);
        if (tot == 255u) {
            __threadfence();
            unsigned win = 0u;
            for (unsigned xx = 0; xx < 16; ++xx) {
                unsigned cx = __hip_atomic_load(&ctrl[40 + xx], __ATOMIC_RELAXED,
                                                __HIP_MEMORY_SCOPE_AGENT);
                if (cx >= 32u) { win = xx; break; }
            }
            __hip_atomic_store(&ctrl[61], win, __ATOMIC_RELAXED,
                               __HIP_MEMORY_SCOPE_AGENT);
        }
        unsigned win;
        do {
            win = __hip_atomic_load(&ctrl[61], __ATOMIC_RELAXED,
                                    __HIP_MEMORY_SCOPE_AGENT);
        } while (win == 0xffffffffu);
        s_chunk = (win == xcc && myidx < 32u) ? (int)myidx : -1;
    }
    __syncthreads();
    const int chunk = s_chunk;
    if (chunk < 0) return;

    const int w = tid >> 6, lane = tid & 63;
    const int col = lane & 15, quad = lane >> 4;
    const int bh = w >> 1, p = w & 1;
    unsigned* s_w32 = (unsigned*)s_w;
    unsigned* s_pack32 = (unsigned*)s_pack;
    unsigned* flags = ctrl;   // ctrl[0..31]
    volatile unsigned* vflags = (volatile unsigned*)ctrl;

    // ---- stage W_hh -> LDS fp8 x256, XOR-swizzled on 8-B blocks ----
    for (int idx = tid; idx < 128 * 256; idx += 256) {
        int r = idx >> 8, dw = idx & 255;
        int g = r >> 5, uu = r & 31, m = chunk * 32 + uu;
        float4 w4 = make_float4(0.f, 0.f, 0.f, 0.f);
        if (m < NH && dw < 250)
            w4 = *(const float4*)&W_hh[(size_t)(g * NH + m) * NH + dw * 4];
        int p0 = __builtin_amdgcn_cvt_pk_fp8_f32(w4.x * WSCALE, w4.y * WSCALE, 0, false);
        int p1 = __builtin_amdgcn_cvt_pk_fp8_f32(w4.z * WSCALE, w4.w * WSCALE, 0, false);
        unsigned v = ((unsigned)p0 & 0xffffu) | ((unsigned)p1 << 16);
        int kb = dw >> 1;
        int kbs = kb ^ (r & 15);
        s_w32[r * 256 + (kbs << 1) + (dw & 1)] = v;
    }
    // ---- zero own chunk of page 0 (plain store -> local L2) ----
    *(unsigned*)(h_q + (size_t)chunk * 1024 + tid * 4) = 0u;
    __syncthreads();   // vmcnt drained -> chunk in L2
    if (tid == 0) vflags[chunk] = 1u;

    // ---- xg prefetch t=0 ----
    s16x4 xcur[4];
#pragma unroll
    for (int g = 0; g < 4; ++g)
        xcur[g] = *(const s16x4*)&xg[((size_t)0 * NJ + chunk * 128 + (2 * g + p) * 16 + col) * NB
                                     + bh * 16 + quad * 4];

    float c[4] = {0.f, 0.f, 0.f, 0.f};
    const int rw = quad * 4;
    const int boff = (bh * 16 + col) * 32 + quad * 8;

    for (int t = 0; t < T_SEQ; ++t) {
        // ---- wait for page t complete: sc0 poll (L2), agent fallback ----
        const unsigned need = (unsigned)(t + 1);
        unsigned spins = 0;
        bool done;
        do {
            unsigned v = need;
            if (lane < 32) {
                if ((++spins & 1023u) == 0u)
                    v = __hip_atomic_load(&flags[lane], __ATOMIC_RELAXED,
                                          __HIP_MEMORY_SCOPE_AGENT);
                else
                    v = poll_sc0(&flags[lane]);
            }
            done = (bool)__all((int)(v >= need));
        } while (!done);

        // ---- burst load page t (plain, fresh addrs, L1 miss -> L2 hit) ----
        const unsigned char* pb = h_q + (size_t)t * 32768 + boff;
        u64 a[32];
#pragma unroll
        for (int kc = 0; kc < 32; ++kc)
            a[kc] = *(const u64*)(pb + (size_t)kc * 1024);

        f32x4 acc0 = {0.f, 0.f, 0.f, 0.f};
        f32x4 acc1 = {0.f, 0.f, 0.f, 0.f};
        f32x4 acc2 = {0.f, 0.f, 0.f, 0.f};
        f32x4 acc3 = {0.f, 0.f, 0.f, 0.f};
#pragma unroll
        for (int kc = 0; kc < 32; ++kc) {
            int kb = kc * 4 + quad;
            u64 b0 = *(const u64*)&s_w[((0 * 2 + p) * 16 + col) * 1024 + ((kb ^ col) << 3)];
            u64 b1 = *(const u64*)&s_w[((1 * 2 + p) * 16 + col) * 1024 + ((kb ^ col) << 3)];
            u64 b2 = *(const u64*)&s_w[((2 * 2 + p) * 16 + col) * 1024 + ((kb ^ col) << 3)];
            u64 b3 = *(const u64*)&s_w[((3 * 2 + p) * 16 + col) * 1024 + ((kb ^ col) << 3)];
            acc0 = __builtin_amdgcn_mfma_f32_16x16x32_fp8_fp8((long)a[kc], (long)b0, acc0, 0, 0, 0);
            acc1 = __builtin_amdgcn_mfma_f32_16x16x32_fp8_fp8((long)a[kc], (long)b1, acc1, 0, 0, 0);
            acc2 = __builtin_amdgcn_mfma_f32_16x16x32_fp8_fp8((long)a[kc], (long)b2, acc2, 0, 0, 0);
            acc3 = __builtin_amdgcn_mfma_f32_16x16x32_fp8_fp8((long)a[kc], (long)b3, acc3, 0, 0, 0);
        }

        // ---- epilogue: 4 cells (b = bh*16+rw+r, u = 16p+col) ----
        float hv[4];
#pragma unroll
        for (int r = 0; r < 4; ++r) {
            float gi = acc0[r] * GSCALE + bf2f((unsigned short)xcur[0][r]);
            float gf = acc1[r] * GSCALE + bf2f((unsigned short)xcur[1][r]);
            float gg = acc2[r] * GSCALE + bf2f((unsigned short)xcur[2][r]);
            float go = acc3[r] * GSCALE + bf2f((unsigned short)xcur[3][r]);
            c[r] = fsig(gf) * c[r] + fsig(gi) * ftanh(gg);
            hv[r] = fsig(go) * ftanh(c[r]);
        }
        // pack fp8 into s_pack[b][u]
        {
            int p01 = __builtin_amdgcn_cvt_pk_fp8_f32(hv[0] * HSCALE, hv[1] * HSCALE, 0, false);
            int p23 = __builtin_amdgcn_cvt_pk_fp8_f32(hv[2] * HSCALE, hv[3] * HSCALE, 0, false);
            s_pack[(bh * 16 + rw + 0) * 32 + p * 16 + col] = (unsigned char)(p01 & 0xff);
            s_pack[(bh * 16 + rw + 1) * 32 + p * 16 + col] = (unsigned char)((p01 >> 8) & 0xff);
            s_pack[(bh * 16 + rw + 2) * 32 + p * 16 + col] = (unsigned char)(p23 & 0xff);
            s_pack[(bh * 16 + rw + 3) * 32 + p * 16 + col] = (unsigned char)((p23 >> 8) & 0xff);
        }
        __syncthreads();   // pack complete
        // plain coalesced 1 KB chunk store -> local L2
        *(unsigned*)(h_q + (size_t)(t + 1) * 32768 + (size_t)chunk * 1024 + tid * 4)
            = s_pack32[tid];
        __syncthreads();   // all waves' store vmcnt drained -> chunk in L2
        if (tid == 0) vflags[chunk] = (unsigned)(t + 2);

        // ---- off critical path: xg prefetch t+1 (completes during next poll) ----
        if (t + 1 < T_SEQ) {
#pragma unroll
            for (int g = 0; g < 4; ++g)
                xcur[g] = *(const s16x4*)&xg[((size_t)(t + 1) * NJ + chunk * 128 + (2 * g + p) * 16 + col) * NB
                                             + bh * 16 + quad * 4];
        }
    }
}

// ---------------------------------------------------------------------------
// tag_gemm (fp8): ts[m][n] = h[m] . lin_w[n]; A = h_q fp8(x16), B = linw_q
// fp8(x512); M=6400, N=16 pad, K=1024 pad. One wave per 16-row tile.
// ---------------------------------------------------------------------------
__global__ __launch_bounds__(64) void tag_gemm(
    const unsigned char* __restrict__ h_q,
    const unsigned char* __restrict__ linw_q, float* __restrict__ ts)
{
    const int m0 = blockIdx.x * 16, lane = threadIdx.x;
    const int col = lane & 15, quad = lane >> 4;
    const int m = m0 + col, t = m >> 5, b = m & 31;
    const unsigned char* pa = h_q + (size_t)(t + 1) * 32768 + b * 32 + quad * 8;
    const unsigned char* pw = linw_q + (size_t)col * 1024 + quad * 8;

    f32x4 acc = {0.f, 0.f, 0.f, 0.f};
#pragma unroll 8
    for (int kc = 0; kc < 32; ++kc) {
        u64 a  = *(const u64*)(pa + (size_t)kc * 1024);
        u64 bv = *(const u64*)(pw + kc * 32);
        acc = __builtin_amdgcn_mfma_f32_16x16x32_fp8_fp8((long)a, (long)bv, acc, 0, 0, 0);
    }
#pragma unroll
    for (int r = 0; r < 4; ++r)
        ts[(size_t)(m0 + quad * 4 + r) * 16 + col] = acc[r] * TSCALE;
}

// ---------------------------------------------------------------------------
__global__ __launch_bounds__(320) void em_kernel(
    const float* __restrict__ ts, const float* __restrict__ lin_b,
    float* __restrict__ em)
{
    __shared__ float s_ts[NB * NK];
    __shared__ float s_lse[NK];
    const int t = blockIdx.x, tid = threadIdx.x;
    float val = 0.f;
    int b = tid / NK, k = tid - b * NK;
    if (tid < NB * NK) {
        val = ts[(size_t)(t * NB + b) * 16 + k] + lin_b[k];
        s_ts[b * NK + k] = val;
    }
    __syncthreads();
    if (tid < NK) {
        float m = -1e30f;
        for (int bb = 0; bb < NB; ++bb) m = fmaxf(m, s_ts[bb * NK + tid]);
        float s = 0.f;
        for (int bb = 0; bb < NB; ++bb) s += __expf(s_ts[bb * NK + tid] - m);
        s_lse[tid] = m + __logf(s);
    }
    __syncthreads();
    if (tid < NB * NK)
        em[((size_t)t * NB + b) * NK + k] = val - s_lse[k];
}

// ---------------------------------------------------------------------------
__global__ __launch_bounds__(320) void crf_kernel(
    const int* __restrict__ y, const float* __restrict__ em,
    const float* __restrict__ start_trans, const float* __restrict__ end_trans,
    const float* __restrict__ trans, float* __restrict__ out)
{
    __shared__ float s_trans[NK * NK];
    __shared__ float s_alpha[NB * NK];
    __shared__ float s_red[NB];
    const int tid = threadIdx.x;
    if (tid < NK * NK) s_trans[tid] = trans[tid];
    __syncthreads();

    float num = 0.f;
    if (tid < NB) {
        int b = tid, yp = y[b];
        num = start_trans[yp] + em[(size_t)b * NK + yp];
        for (int t = 1; t < T_SEQ; ++t) {
            int yc = y[t * NB + b];
            num += s_trans[yp * NK + yc] + em[((size_t)t * NB + b) * NK + yc];
            yp = yc;
        }
        num += end_trans[yp];
    }

    const int b = tid / NK, k = tid - (tid / NK) * NK;
    if (tid < NB * NK)
        s_alpha[tid] = start_trans[k] + em[(size_t)b * NK + k];
    __syncthreads();

    for (int t = 1; t < T_SEQ; ++t) {
        float nv = 0.f;
        if (tid < NB * NK) {
            float m = -1e30f;
#pragma unroll
            for (int i = 0; i < NK; ++i)
                m = fmaxf(m, s_alpha[b * NK + i] + s_trans[i * NK + k]);
            float s = 0.f;
#pragma unroll
            for (int i = 0; i < NK; ++i)
                s += __expf(s_alpha[b * NK + i] + s_trans[i * NK + k] - m);
            nv = em[((size_t)t * NB + b) * NK + k] + m + __logf(s);
        }
        __syncthreads();
        if (tid < NB * NK) s_alpha[tid] = nv;
        __syncthreads();
    }

    if (tid < NB) {
        float m = -1e30f;
        for (int k2 = 0; k2 < NK; ++k2)
            m = fmaxf(m, s_alpha[tid * NK + k2] + end_trans[k2]);
        float s = 0.f;
        for (int k2 = 0; k2 < NK; ++k2)
            s += __expf(s_alpha[tid * NK + k2] + end_trans[k2] - m);
        s_red[tid] = num - (m + __logf(s));
    }
    __syncthreads();
    if (tid == 0) {
        float tot = 0.f;
        for (int i = 0; i < NB; ++i) tot += s_red[i];
        out[0] = tot;
    }
}

// ---------------------------------------------------------------------------
extern "C" void kernel_launch(void* const* d_in, const int* in_sizes, int n_in,
                              void* d_out, int out_size, void* d_ws, size_t ws_size,
                              hipStream_t stream)
{
    const int*   x           = (const int*)d_in[0];
    const int*   y           = (const int*)d_in[1];
    const float* embed_w     = (const float*)d_in[2];
    const float* W_ih        = (const float*)d_in[3];
    const float* W_hh        = (const float*)d_in[4];
    const float* b_ih        = (const float*)d_in[5];
    const float* b_hh        = (const float*)d_in[6];
    const float* lin_w       = (const float*)d_in[7];
    const float* lin_b       = (const float*)d_in[8];
    const float* start_trans = (const float*)d_in[9];
    const float* end_trans   = (const float*)d_in[10];
    const float* trans       = (const float*)d_in[11];
    float* out = (float*)d_out;

    char* ws = (char*)d_ws;
    unsigned short* xg     = (unsigned short*)(ws);               // 52,428,800 B
    float*          ts     = (float*)(ws);                        // aliases xg (dead post-lstm)
    unsigned char*  linw_q = (unsigned char*)(ws + 52428800);     //     16,384 B
    float*          em     = (float*)(ws + 65601536);             //    230,400 B
    unsigned*       ctrl   = (unsigned*)(ws + 65831936);          //      8,192 B
    float*          biasg  = (float*)(ws + 65840128);             //     16,384 B
    unsigned short* emb_bf = (unsigned short*)(ws + 65856512);    //  4,096,000 B
    unsigned short* wih_bf = (unsigned short*)(ws + 69952512);    //  2,621,440 B
    unsigned char*  h_q    = (unsigned char*)(ws + 65856512);     //  6,586,368 B (overlay)

    prep_emb<<<dim3(T_SEQ), 256, 0, stream>>>(x, embed_w, emb_bf, ctrl);
    prep_w<<<dim3(64), 256, 0, stream>>>(W_ih, b_ih, b_hh, lin_w, wih_bf, biasg, linw_q);
    proj_kernel<<<dim3(64, T_SEQ), 256, 0, stream>>>(emb_bf, wih_bf, biasg, xg);

    lstm_kernel<<<dim3(256), 256, 0, stream>>>(W_hh, xg, h_q, ctrl);

    tag_gemm<<<dim3(400), 64, 0, stream>>>(h_q, linw_q, ts);
    em_kernel<<<dim3(T_SEQ), 320, 0, stream>>>(ts, lin_b, em);
    crf_kernel<<<dim3(1), 320, 0, stream>>>(y, em, start_trans, end_trans, trans, out);
}

// Round 11
// 1381.281 us; speedup vs baseline: 16.1162x; 16.1162x over previous
//
#include <hip/hip_runtime.h>

#define T_SEQ 200
#define NB    32
#define NE    300
#define NH    1000
#define NK    9
#define NJ    4096          // xg rows per t
#define EPD   320           // padded embed K
#define WSCALE 256.0f
#define HSCALE 16.0f
#define LSCALE 512.0f
#define GSCALE (1.0f / (256.0f * 16.0f))
#define TSCALE (1.0f / (16.0f * 512.0f))

typedef __attribute__((ext_vector_type(4))) float f32x4;
typedef __attribute__((ext_vector_type(8))) short s16x8;
typedef __attribute__((ext_vector_type(4))) short s16x4;
typedef unsigned long long u64;

__device__ __forceinline__ unsigned short f2bf(float f) {
    union { float f; unsigned u; } v; v.f = f;
    unsigned r = v.u + 0x7FFFu + ((v.u >> 16) & 1u);   // RNE
    return (unsigned short)(r >> 16);
}
__device__ __forceinline__ float bf2f(unsigned short h) {
    union { unsigned u; float f; } v; v.u = ((unsigned)h) << 16;
    return v.f;
}
__device__ __forceinline__ float ftanh(float x) {
    float e = __expf(fminf(2.f * x, 80.f));
    return (e - 1.f) / (e + 1.f);
}
__device__ __forceinline__ float fsig(float x) {
    return 1.f / (1.f + __expf(-x));
}

// ---------------------------------------------------------------------------
// prep_emb: gather+convert embeds -> bf16; block 0 inits ctrl block
// ctrl[0..31]=h flags, ctrl[40..55]=XCD tickets, ctrl[60]=arrivals,
// ctrl[61]=winner sentinel, ctrl[62]=producer ticket, ctrl[256..455]=done[t]
// ---------------------------------------------------------------------------
__global__ __launch_bounds__(256) void prep_emb(
    const int* __restrict__ x, const float* __restrict__ embed_w,
    unsigned short* __restrict__ emb_bf, unsigned* __restrict__ ctrl)
{
    const int t = blockIdx.x, tid = threadIdx.x;
    if (blockIdx.x == 0) {
        for (int i = tid; i < 2048; i += 256)
            ctrl[i] = (i == 61) ? 0xffffffffu : 0u;
    }
    for (int idx = tid; idx < NB * EPD; idx += 256) {
        int b = idx / EPD, e = idx - b * EPD;
        float v = (e < NE) ? embed_w[(size_t)x[t * NB + b] * NE + e] : 0.f;
        emb_bf[((size_t)t * NB + b) * EPD + e] = f2bf(v);
    }
}

// ---------------------------------------------------------------------------
// prep_w: W_ih -> bf16 [jp][320]; blocks 0..15 quantize lin_w row n=blk
// ---------------------------------------------------------------------------
__global__ __launch_bounds__(256) void prep_w(
    const float* __restrict__ W_ih, const float* __restrict__ b_ih,
    const float* __restrict__ b_hh, const float* __restrict__ lin_w,
    unsigned short* __restrict__ wih_bf, float* __restrict__ biasg,
    unsigned char* __restrict__ linw_q)
{
    const int blk = blockIdx.x, tid = threadIdx.x;
    for (int idx = tid; idx < 64 * EPD; idx += 256) {
        int jr = idx / EPD, e = idx - jr * EPD;
        int jp = blk * 64 + jr;
        int wgu = jp >> 7, rr = jp & 127, g = rr >> 5, uu = rr & 31;
        int m = wgu * 32 + uu;
        float v = (m < NH && e < NE) ? W_ih[(size_t)(g * NH + m) * NE + e] : 0.f;
        wih_bf[(size_t)jp * EPD + e] = f2bf(v);
    }
    if (tid < 64) {
        int jp = blk * 64 + tid;
        int wgu = jp >> 7, rr = jp & 127, g = rr >> 5, uu = rr & 31;
        int m = wgu * 32 + uu;
        biasg[jp] = (m < NH) ? (b_ih[g * NH + m] + b_hh[g * NH + m]) : 0.f;
    }
    if (blk < 16) {
        int n = blk, k = tid * 4;
        float v0 = (n < NK && k + 0 < NH) ? lin_w[(size_t)n * NH + k + 0] * LSCALE : 0.f;
        float v1 = (n < NK && k + 1 < NH) ? lin_w[(size_t)n * NH + k + 1] * LSCALE : 0.f;
        float v2 = (n < NK && k + 2 < NH) ? lin_w[(size_t)n * NH + k + 2] * LSCALE : 0.f;
        float v3 = (n < NK && k + 3 < NH) ? lin_w[(size_t)n * NH + k + 3] * LSCALE : 0.f;
        int p01 = __builtin_amdgcn_cvt_pk_fp8_f32(v0, v1, 0, false);
        int p23 = __builtin_amdgcn_cvt_pk_fp8_f32(v2, v3, 0, false);
        ((unsigned*)linw_q)[n * 256 + tid] =
            ((unsigned)p01 & 0xffffu) | ((unsigned)p23 << 16);
    }
}

// ---------------------------------------------------------------------------
// gate: advance `ready` (xg pages complete) until ready > tn. 8 done[] words
// per poll round (one cacheline), prefix-run counted via ballot.
// ---------------------------------------------------------------------------
__device__ __forceinline__ int gate_xg(unsigned* done, int ready, int tn, int lane) {
    while (ready <= tn) {
        unsigned v = 64u;
        if (lane < 8 && ready + lane < T_SEQ)
            v = __hip_atomic_load(&done[ready + lane], __ATOMIC_RELAXED,
                                  __HIP_MEMORY_SCOPE_AGENT);
        unsigned m = (unsigned)__ballot((int)(v >= 64u)) & 255u;
        if (m & 1u) {
            unsigned run = (m == 255u) ? 8u : (unsigned)__builtin_ctz(~m);
            ready += (int)run;
        } else {
            __builtin_amdgcn_s_sleep(1);
        }
    }
    return ready;
}

// ---------------------------------------------------------------------------
// mega kernel: grid 256, 1 WG/CU (132 KB LDS) => all co-resident.
// Election picks one XCD: its 32 WGs = consumers (recurrence, R9-proven sync);
// the other 224 WGs = producers (xg projection tiles, t-ascending,
// agent-atomic stores -> MALL, done[t] counters).
// ---------------------------------------------------------------------------
__global__ __launch_bounds__(256, 1) void lstm_kernel(
    const float* __restrict__ W_hh,
    const unsigned short* __restrict__ emb_bf,
    const unsigned short* __restrict__ wih_bf,
    const float* __restrict__ biasg,
    unsigned short* __restrict__ xg,
    unsigned char* __restrict__ h_q,
    unsigned* __restrict__ ctrl)
{
    __shared__ __align__(16) unsigned char s_w[128 * 1024];   // 131,072 B
    __shared__ __align__(4) unsigned char s_pack[1024];
    __shared__ int s_chunk, s_pid;

    const int tid = threadIdx.x;

    // ---- election (startup only, MALL atomics; R9-proven) ----
    if (tid == 0) {
        unsigned xcc;
        asm volatile("s_getreg_b32 %0, hwreg(HW_REG_XCC_ID)" : "=s"(xcc));
        xcc &= 15u;
        unsigned myidx = __hip_atomic_fetch_add(&ctrl[40 + xcc], 1u,
                             __ATOMIC_RELAXED, __HIP_MEMORY_SCOPE_AGENT);
        __threadfence();
        unsigned tot = __hip_atomic_fetch_add(&ctrl[60], 1u,
                             __ATOMIC_RELAXED, __HIP_MEMORY_SCOPE_AGENT);
        if (tot == 255u) {
            __threadfence();
            unsigned win = 0u;
            for (unsigned xx = 0; xx < 16; ++xx) {
                unsigned cx = __hip_atomic_load(&ctrl[40 + xx], __ATOMIC_RELAXED,
                                                __HIP_MEMORY_SCOPE_AGENT);
                if (cx >= 32u) { win = xx; break; }
            }
            __hip_atomic_store(&ctrl[61], win, __ATOMIC_RELAXED,
                               __HIP_MEMORY_SCOPE_AGENT);
        }
        unsigned win;
        do {
            win = __hip_atomic_load(&ctrl[61], __ATOMIC_RELAXED,
                                    __HIP_MEMORY_SCOPE_AGENT);
        } while (win == 0xffffffffu);
        bool cons = (win == xcc && myidx < 32u);
        s_chunk = cons ? (int)myidx : -1;
        s_pid = cons ? -1
                     : (int)__hip_atomic_fetch_add(&ctrl[62], 1u,
                           __ATOMIC_RELAXED, __HIP_MEMORY_SCOPE_AGENT);
    }
    __syncthreads();
    const int chunk = s_chunk;
    const int w = tid >> 6, lane = tid & 63;
    const int col = lane & 15, quad = lane >> 4;
    unsigned* flags = ctrl;          // ctrl[0..31]
    unsigned* done  = ctrl + 256;    // ctrl[256..455]

    if (chunk < 0) {
        // =================== PRODUCER: xg projection tiles ===================
        const int pid = s_pid;
        for (int g = pid; g < T_SEQ * 64; g += 224) {
            const int t = g >> 6, jt = g & 63;
            const unsigned short* eb = emb_bf + (size_t)t * NB * EPD;
            const unsigned short* wb = wih_bf + (size_t)(jt * 64 + w * 16 + col) * EPD;
            const unsigned short* ea0 = eb + (size_t)col * EPD;
            const unsigned short* ea1 = eb + (size_t)(16 + col) * EPD;

            f32x4 acc0 = {0.f, 0.f, 0.f, 0.f};
            f32x4 acc1 = {0.f, 0.f, 0.f, 0.f};
#pragma unroll
            for (int kc = 0; kc < EPD / 32; ++kc) {
                int ko = kc * 32 + quad * 8;
                s16x8 a0 = *(const s16x8*)&ea0[ko];
                s16x8 a1 = *(const s16x8*)&ea1[ko];
                s16x8 bb = *(const s16x8*)&wb[ko];
                acc0 = __builtin_amdgcn_mfma_f32_16x16x32_bf16(a0, bb, acc0, 0, 0, 0);
                acc1 = __builtin_amdgcn_mfma_f32_16x16x32_bf16(a1, bb, acc1, 0, 0, 0);
            }
            const int jp = jt * 64 + w * 16 + col;
            const float bi = biasg[jp];
            size_t base = ((size_t)t * NJ + jp) * NB;
            union { s16x4 v; u64 q; } p0, p1;
#pragma unroll
            for (int r = 0; r < 4; ++r) {
                p0.v[r] = (short)f2bf(acc0[r] + bi);
                p1.v[r] = (short)f2bf(acc1[r] + bi);
            }
            // agent atomic stores: write-through to MALL (cross-XCD visible)
            __hip_atomic_store((u64*)&xg[base + quad * 4], p0.q,
                               __ATOMIC_RELAXED, __HIP_MEMORY_SCOPE_AGENT);
            __hip_atomic_store((u64*)&xg[base + 16 + quad * 4], p1.q,
                               __ATOMIC_RELAXED, __HIP_MEMORY_SCOPE_AGENT);
            __syncthreads();   // all waves' stores vmcnt-drained (MALL-ack'd)
            if (tid == 0)
                __hip_atomic_fetch_add(&done[t], 1u, __ATOMIC_RELAXED,
                                       __HIP_MEMORY_SCOPE_AGENT);
        }
        return;
    }

    // ===================== CONSUMER: LSTM recurrence =====================
    const int bh = w >> 1, p = w & 1;
    unsigned* s_w32 = (unsigned*)s_w;
    unsigned* s_pack32 = (unsigned*)s_pack;

    // ---- stage W_hh -> LDS fp8 x256, XOR-swizzled on 8-B blocks ----
    for (int idx = tid; idx < 128 * 256; idx += 256) {
        int r = idx >> 8, dw = idx & 255;
        int g = r >> 5, uu = r & 31, m = chunk * 32 + uu;
        float4 w4 = make_float4(0.f, 0.f, 0.f, 0.f);
        if (m < NH && dw < 250)
            w4 = *(const float4*)&W_hh[(size_t)(g * NH + m) * NH + dw * 4];
        int p0 = __builtin_amdgcn_cvt_pk_fp8_f32(w4.x * WSCALE, w4.y * WSCALE, 0, false);
        int p1 = __builtin_amdgcn_cvt_pk_fp8_f32(w4.z * WSCALE, w4.w * WSCALE, 0, false);
        unsigned v = ((unsigned)p0 & 0xffffu) | ((unsigned)p1 << 16);
        int kb = dw >> 1;
        int kbs = kb ^ (r & 15);
        s_w32[r * 256 + (kbs << 1) + (dw & 1)] = v;
    }
    // ---- zero own chunk of page 0 (plain store -> local L2; R9-proven) ----
    *(unsigned*)(h_q + (size_t)chunk * 1024 + tid * 4) = 0u;
    __syncthreads();
    if (tid == 0)
        __hip_atomic_store(&flags[chunk], 1u, __ATOMIC_RELAXED, __HIP_MEMORY_SCOPE_AGENT);

    // ---- gated xg prefetch t=0 ----
    int ready = 0;
    ready = gate_xg(done, ready, 0, lane);
    s16x4 xcur[4];
#pragma unroll
    for (int g = 0; g < 4; ++g)
        xcur[g] = *(const s16x4*)&xg[((size_t)0 * NJ + chunk * 128 + (2 * g + p) * 16 + col) * NB
                                     + bh * 16 + quad * 4];

    float c[4] = {0.f, 0.f, 0.f, 0.f};
    const int rw = quad * 4;
    const int boff = (bh * 16 + col) * 32 + quad * 8;

    for (int t = 0; t < T_SEQ; ++t) {
        // ---- wait for h page t complete (agent poll, R9-proven) ----
        const unsigned need = (unsigned)(t + 1);
        bool ok;
        do {
            unsigned v = (lane < 32)
                ? __hip_atomic_load(&flags[lane], __ATOMIC_RELAXED, __HIP_MEMORY_SCOPE_AGENT)
                : need;
            ok = (bool)__all((int)(v >= need));
        } while (!ok);
        asm volatile("" ::: "memory");

        // ---- burst load page t (plain, fresh addrs, local L2) ----
        const unsigned char* pb = h_q + (size_t)t * 32768 + boff;
        u64 a[32];
#pragma unroll
        for (int kc = 0; kc < 32; ++kc)
            a[kc] = *(const u64*)(pb + (size_t)kc * 1024);

        f32x4 acc0 = {0.f, 0.f, 0.f, 0.f};
        f32x4 acc1 = {0.f, 0.f, 0.f, 0.f};
        f32x4 acc2 = {0.f, 0.f, 0.f, 0.f};
        f32x4 acc3 = {0.f, 0.f, 0.f, 0.f};
#pragma unroll
        for (int kc = 0; kc < 32; ++kc) {
            int kb = kc * 4 + quad;
            u64 b0 = *(const u64*)&s_w[((0 * 2 + p) * 16 + col) * 1024 + ((kb ^ col) << 3)];
            u64 b1 = *(const u64*)&s_w[((1 * 2 + p) * 16 + col) * 1024 + ((kb ^ col) << 3)];
            u64 b2 = *(const u64*)&s_w[((2 * 2 + p) * 16 + col) * 1024 + ((kb ^ col) << 3)];
            u64 b3 = *(const u64*)&s_w[((3 * 2 + p) * 16 + col) * 1024 + ((kb ^ col) << 3)];
            acc0 = __builtin_amdgcn_mfma_f32_16x16x32_fp8_fp8((long)a[kc], (long)b0, acc0, 0, 0, 0);
            acc1 = __builtin_amdgcn_mfma_f32_16x16x32_fp8_fp8((long)a[kc], (long)b1, acc1, 0, 0, 0);
            acc2 = __builtin_amdgcn_mfma_f32_16x16x32_fp8_fp8((long)a[kc], (long)b2, acc2, 0, 0, 0);
            acc3 = __builtin_amdgcn_mfma_f32_16x16x32_fp8_fp8((long)a[kc], (long)b3, acc3, 0, 0, 0);
        }

        // ---- epilogue: 4 cells (b = bh*16+rw+r, u = 16p+col) ----
        float hv[4];
#pragma unroll
        for (int r = 0; r < 4; ++r) {
            float gi = acc0[r] * GSCALE + bf2f((unsigned short)xcur[0][r]);
            float gf = acc1[r] * GSCALE + bf2f((unsigned short)xcur[1][r]);
            float gg = acc2[r] * GSCALE + bf2f((unsigned short)xcur[2][r]);
            float go = acc3[r] * GSCALE + bf2f((unsigned short)xcur[3][r]);
            c[r] = fsig(gf) * c[r] + fsig(gi) * ftanh(gg);
            hv[r] = fsig(go) * ftanh(c[r]);
        }
        {
            int p01 = __builtin_amdgcn_cvt_pk_fp8_f32(hv[0] * HSCALE, hv[1] * HSCALE, 0, false);
            int p23 = __builtin_amdgcn_cvt_pk_fp8_f32(hv[2] * HSCALE, hv[3] * HSCALE, 0, false);
            s_pack[(bh * 16 + rw + 0) * 32 + p * 16 + col] = (unsigned char)(p01 & 0xff);
            s_pack[(bh * 16 + rw + 1) * 32 + p * 16 + col] = (unsigned char)((p01 >> 8) & 0xff);
            s_pack[(bh * 16 + rw + 2) * 32 + p * 16 + col] = (unsigned char)(p23 & 0xff);
            s_pack[(bh * 16 + rw + 3) * 32 + p * 16 + col] = (unsigned char)((p23 >> 8) & 0xff);
        }
        __syncthreads();
        *(unsigned*)(h_q + (size_t)(t + 1) * 32768 + (size_t)chunk * 1024 + tid * 4)
            = s_pack32[tid];
        __syncthreads();   // stores drained -> chunk in local L2
        if (tid == 0)
            __hip_atomic_store(&flags[chunk], (unsigned)(t + 2),
                               __ATOMIC_RELAXED, __HIP_MEMORY_SCOPE_AGENT);

        // ---- off critical path: gated xg prefetch t+1 ----
        if (t + 1 < T_SEQ) {
            ready = gate_xg(done, ready, t + 1, lane);
#pragma unroll
            for (int g = 0; g < 4; ++g)
                xcur[g] = *(const s16x4*)&xg[((size_t)(t + 1) * NJ + chunk * 128 + (2 * g + p) * 16 + col) * NB
                                             + bh * 16 + quad * 4];
        }
    }
}

// ---------------------------------------------------------------------------
// tag_gemm (fp8): ts[m][n] = h[m] . lin_w[n]; A = h_q fp8(x16), B = linw_q
// ---------------------------------------------------------------------------
__global__ __launch_bounds__(64) void tag_gemm(
    const unsigned char* __restrict__ h_q,
    const unsigned char* __restrict__ linw_q, float* __restrict__ ts)
{
    const int m0 = blockIdx.x * 16, lane = threadIdx.x;
    const int col = lane & 15, quad = lane >> 4;
    const int m = m0 + col, t = m >> 5, b = m & 31;
    const unsigned char* pa = h_q + (size_t)(t + 1) * 32768 + b * 32 + quad * 8;
    const unsigned char* pw = linw_q + (size_t)col * 1024 + quad * 8;

    f32x4 acc = {0.f, 0.f, 0.f, 0.f};
#pragma unroll 8
    for (int kc = 0; kc < 32; ++kc) {
        u64 a  = *(const u64*)(pa + (size_t)kc * 1024);
        u64 bv = *(const u64*)(pw + kc * 32);
        acc = __builtin_amdgcn_mfma_f32_16x16x32_fp8_fp8((long)a, (long)bv, acc, 0, 0, 0);
    }
#pragma unroll
    for (int r = 0; r < 4; ++r)
        ts[(size_t)(m0 + quad * 4 + r) * 16 + col] = acc[r] * TSCALE;
}

// ---------------------------------------------------------------------------
__global__ __launch_bounds__(320) void em_kernel(
    const float* __restrict__ ts, const float* __restrict__ lin_b,
    float* __restrict__ em)
{
    __shared__ float s_ts[NB * NK];
    __shared__ float s_lse[NK];
    const int t = blockIdx.x, tid = threadIdx.x;
    float val = 0.f;
    int b = tid / NK, k = tid - b * NK;
    if (tid < NB * NK) {
        val = ts[(size_t)(t * NB + b) * 16 + k] + lin_b[k];
        s_ts[b * NK + k] = val;
    }
    __syncthreads();
    if (tid < NK) {
        float m = -1e30f;
        for (int bb = 0; bb < NB; ++bb) m = fmaxf(m, s_ts[bb * NK + tid]);
        float s = 0.f;
        for (int bb = 0; bb < NB; ++bb) s += __expf(s_ts[bb * NK + tid] - m);
        s_lse[tid] = m + __logf(s);
    }
    __syncthreads();
    if (tid < NB * NK)
        em[((size_t)t * NB + b) * NK + k] = val - s_lse[k];
}

// ---------------------------------------------------------------------------
__global__ __launch_bounds__(320) void crf_kernel(
    const int* __restrict__ y, const float* __restrict__ em,
    const float* __restrict__ start_trans, const float* __restrict__ end_trans,
    const float* __restrict__ trans, float* __restrict__ out)
{
    __shared__ float s_trans[NK * NK];
    __shared__ float s_alpha[NB * NK];
    __shared__ float s_red[NB];
    const int tid = threadIdx.x;
    if (tid < NK * NK) s_trans[tid] = trans[tid];
    __syncthreads();

    float num = 0.f;
    if (tid < NB) {
        int b = tid, yp = y[b];
        num = start_trans[yp] + em[(size_t)b * NK + yp];
        for (int t = 1; t < T_SEQ; ++t) {
            int yc = y[t * NB + b];
            num += s_trans[yp * NK + yc] + em[((size_t)t * NB + b) * NK + yc];
            yp = yc;
        }
        num += end_trans[yp];
    }

    const int b = tid / NK, k = tid - (tid / NK) * NK;
    if (tid < NB * NK)
        s_alpha[tid] = start_trans[k] + em[(size_t)b * NK + k];
    __syncthreads();

    for (int t = 1; t < T_SEQ; ++t) {
        float nv = 0.f;
        if (tid < NB * NK) {
            float m = -1e30f;
#pragma unroll
            for (int i = 0; i < NK; ++i)
                m = fmaxf(m, s_alpha[b * NK + i] + s_trans[i * NK + k]);
            float s = 0.f;
#pragma unroll
            for (int i = 0; i < NK; ++i)
                s += __expf(s_alpha[b * NK + i] + s_trans[i * NK + k] - m);
            nv = em[((size_t)t * NB + b) * NK + k] + m + __logf(s);
        }
        __syncthreads();
        if (tid < NB * NK) s_alpha[tid] = nv;
        __syncthreads();
    }

    if (tid < NB) {
        float m = -1e30f;
        for (int k2 = 0; k2 < NK; ++k2)
            m = fmaxf(m, s_alpha[tid * NK + k2] + end_trans[k2]);
        float s = 0.f;
        for (int k2 = 0; k2 < NK; ++k2)
            s += __expf(s_alpha[tid * NK + k2] + end_trans[k2] - m);
        s_red[tid] = num - (m + __logf(s));
    }
    __syncthreads();
    if (tid == 0) {
        float tot = 0.f;
        for (int i = 0; i < NB; ++i) tot += s_red[i];
        out[0] = tot;
    }
}

// ---------------------------------------------------------------------------
extern "C" void kernel_launch(void* const* d_in, const int* in_sizes, int n_in,
                              void* d_out, int out_size, void* d_ws, size_t ws_size,
                              hipStream_t stream)
{
    const int*   x           = (const int*)d_in[0];
    const int*   y           = (const int*)d_in[1];
    const float* embed_w     = (const float*)d_in[2];
    const float* W_ih        = (const float*)d_in[3];
    const float* W_hh        = (const float*)d_in[4];
    const float* b_ih        = (const float*)d_in[5];
    const float* b_hh        = (const float*)d_in[6];
    const float* lin_w       = (const float*)d_in[7];
    const float* lin_b       = (const float*)d_in[8];
    const float* start_trans = (const float*)d_in[9];
    const float* end_trans   = (const float*)d_in[10];
    const float* trans       = (const float*)d_in[11];
    float* out = (float*)d_out;

    char* ws = (char*)d_ws;
    unsigned short* xg     = (unsigned short*)(ws);               // 52,428,800 B
    float*          ts     = (float*)(ws);                        // aliases xg (dead post-lstm)
    unsigned char*  h_q    = (unsigned char*)(ws + 52428800);     //  6,586,368 B
    unsigned char*  linw_q = (unsigned char*)(ws + 59015168);     //     16,384 B
    float*          em     = (float*)(ws + 65601536);             //    230,400 B
    unsigned*       ctrl   = (unsigned*)(ws + 65831936);          //      8,192 B
    float*          biasg  = (float*)(ws + 65840128);             //     16,384 B
    unsigned short* emb_bf = (unsigned short*)(ws + 65856512);    //  4,096,000 B
    unsigned short* wih_bf = (unsigned short*)(ws + 69952512);    //  2,621,440 B

    prep_emb<<<dim3(T_SEQ), 256, 0, stream>>>(x, embed_w, emb_bf, ctrl);
    prep_w<<<dim3(64), 256, 0, stream>>>(W_ih, b_ih, b_hh, lin_w, wih_bf, biasg, linw_q);

    lstm_kernel<<<dim3(256), 256, 0, stream>>>(W_hh, emb_bf, wih_bf, biasg,
                                               xg, h_q, ctrl);

    tag_gemm<<<dim3(400), 64, 0, stream>>>(h_q, linw_q, ts);
    em_kernel<<<dim3(T_SEQ), 320, 0, stream>>>(ts, lin_b, em);
    crf_kernel<<<dim3(1), 320, 0, stream>>>(y, em, start_trans, end_trans, trans, out);
}

// Round 12
// 1375.417 us; speedup vs baseline: 16.1849x; 1.0043x over previous
//
#include <hip/hip_runtime.h>

#define T_SEQ 200
#define NB    32
#define NE    300
#define NH    1000
#define NK    9
#define NJ    4096          // xg rows per t
#define EPD   320           // padded embed K
#define WSCALE 256.0f
#define HSCALE 16.0f
#define LSCALE 512.0f
#define GSCALE (1.0f / (256.0f * 16.0f))
#define TSCALE (1.0f / (16.0f * 512.0f))

typedef __attribute__((ext_vector_type(4))) float f32x4;
typedef __attribute__((ext_vector_type(8))) short s16x8;
typedef __attribute__((ext_vector_type(4))) short s16x4;
typedef unsigned long long u64;

__device__ __forceinline__ unsigned short f2bf(float f) {
    union { float f; unsigned u; } v; v.f = f;
    unsigned r = v.u + 0x7FFFu + ((v.u >> 16) & 1u);   // RNE
    return (unsigned short)(r >> 16);
}
__device__ __forceinline__ float bf2f(unsigned short h) {
    union { unsigned u; float f; } v; v.u = ((unsigned)h) << 16;
    return v.f;
}
__device__ __forceinline__ float ftanh(float x) {
    float e = __expf(fminf(2.f * x, 80.f));
    return (e - 1.f) / (e + 1.f);
}
__device__ __forceinline__ float fsig(float x) {
    return 1.f / (1.f + __expf(-x));
}
// non-temporal dword load: no L1 allocate -> always served by (XCD) L2
__device__ __forceinline__ unsigned nt_poll(const unsigned* p) {
    unsigned r;
    asm volatile("global_load_dword %0, %1, off nt\n\t"
                 "s_waitcnt vmcnt(0)"
                 : "=v"(r) : "v"(p) : "memory");
    return r;
}

// ---------------------------------------------------------------------------
// ctrl map: [0..31] slow flags (agent/MALL) | [64..95] fast flags (plain/L2)
// [40..55] XCD tickets | [60] arrivals | [61] winner | [62] producer ticket
// [63] heater stop | [256..455] done[t]
// ---------------------------------------------------------------------------
__global__ __launch_bounds__(256) void prep_emb(
    const int* __restrict__ x, const float* __restrict__ embed_w,
    unsigned short* __restrict__ emb_bf, unsigned* __restrict__ ctrl)
{
    const int t = blockIdx.x, tid = threadIdx.x;
    if (blockIdx.x == 0) {
        for (int i = tid; i < 2048; i += 256)
            ctrl[i] = (i == 61) ? 0xffffffffu : 0u;
    }
    for (int idx = tid; idx < NB * EPD; idx += 256) {
        int b = idx / EPD, e = idx - b * EPD;
        float v = (e < NE) ? embed_w[(size_t)x[t * NB + b] * NE + e] : 0.f;
        emb_bf[((size_t)t * NB + b) * EPD + e] = f2bf(v);
    }
}

// ---------------------------------------------------------------------------
__global__ __launch_bounds__(256) void prep_w(
    const float* __restrict__ W_ih, const float* __restrict__ b_ih,
    const float* __restrict__ b_hh, const float* __restrict__ lin_w,
    unsigned short* __restrict__ wih_bf, float* __restrict__ biasg,
    unsigned char* __restrict__ linw_q)
{
    const int blk = blockIdx.x, tid = threadIdx.x;
    for (int idx = tid; idx < 64 * EPD; idx += 256) {
        int jr = idx / EPD, e = idx - jr * EPD;
        int jp = blk * 64 + jr;
        int wgu = jp >> 7, rr = jp & 127, g = rr >> 5, uu = rr & 31;
        int m = wgu * 32 + uu;
        float v = (m < NH && e < NE) ? W_ih[(size_t)(g * NH + m) * NE + e] : 0.f;
        wih_bf[(size_t)jp * EPD + e] = f2bf(v);
    }
    if (tid < 64) {
        int jp = blk * 64 + tid;
        int wgu = jp >> 7, rr = jp & 127, g = rr >> 5, uu = rr & 31;
        int m = wgu * 32 + uu;
        biasg[jp] = (m < NH) ? (b_ih[g * NH + m] + b_hh[g * NH + m]) : 0.f;
    }
    if (blk < 16) {
        int n = blk, k = tid * 4;
        float v0 = (n < NK && k + 0 < NH) ? lin_w[(size_t)n * NH + k + 0] * LSCALE : 0.f;
        float v1 = (n < NK && k + 1 < NH) ? lin_w[(size_t)n * NH + k + 1] * LSCALE : 0.f;
        float v2 = (n < NK && k + 2 < NH) ? lin_w[(size_t)n * NH + k + 2] * LSCALE : 0.f;
        float v3 = (n < NK && k + 3 < NH) ? lin_w[(size_t)n * NH + k + 3] * LSCALE : 0.f;
        int p01 = __builtin_amdgcn_cvt_pk_fp8_f32(v0, v1, 0, false);
        int p23 = __builtin_amdgcn_cvt_pk_fp8_f32(v2, v3, 0, false);
        ((unsigned*)linw_q)[n * 256 + tid] =
            ((unsigned)p01 & 0xffffu) | ((unsigned)p23 << 16);
    }
}

// ---------------------------------------------------------------------------
__device__ __forceinline__ int gate_xg(unsigned* done, int ready, int tn, int lane) {
    while (ready <= tn) {
        unsigned v = 64u;
        if (lane < 8 && ready + lane < T_SEQ)
            v = __hip_atomic_load(&done[ready + lane], __ATOMIC_RELAXED,
                                  __HIP_MEMORY_SCOPE_AGENT);
        unsigned m = (unsigned)__ballot((int)(v >= 64u)) & 255u;
        if (m & 1u) {
            unsigned run = (m == 255u) ? 8u : (unsigned)__builtin_ctz(~m);
            ready += (int)run;
        } else {
            __builtin_amdgcn_s_sleep(1);
        }
    }
    return ready;
}

// ---------------------------------------------------------------------------
// mega kernel: grid 256, 1 WG/CU. Winner XCD's 32 WGs = consumers; other 224
// = producers (xg tiles) then HEATERS (dependent-FMA spin holds DPM clocks).
// Consumer sync: fast flags plain-stored -> XCD L2, nt-load polled; slow
// agent copy polled every 8th spin (can't hang).
// ---------------------------------------------------------------------------
__global__ __launch_bounds__(256, 1) void lstm_kernel(
    const float* __restrict__ W_hh,
    const unsigned short* __restrict__ emb_bf,
    const unsigned short* __restrict__ wih_bf,
    const float* __restrict__ biasg,
    unsigned short* __restrict__ xg,
    unsigned char* __restrict__ h_q,
    unsigned* __restrict__ ctrl)
{
    __shared__ __align__(16) unsigned char s_w[128 * 1024];   // 131,072 B
    __shared__ int s_chunk, s_pid;

    const int tid = threadIdx.x;

    // ---- election (startup only, MALL atomics; R9-proven) ----
    if (tid == 0) {
        unsigned xcc;
        asm volatile("s_getreg_b32 %0, hwreg(HW_REG_XCC_ID)" : "=s"(xcc));
        xcc &= 15u;
        unsigned myidx = __hip_atomic_fetch_add(&ctrl[40 + xcc], 1u,
                             __ATOMIC_RELAXED, __HIP_MEMORY_SCOPE_AGENT);
        __threadfence();
        unsigned tot = __hip_atomic_fetch_add(&ctrl[60], 1u,
                             __ATOMIC_RELAXED, __HIP_MEMORY_SCOPE_AGENT);
        if (tot == 255u) {
            __threadfence();
            unsigned win = 0u;
            for (unsigned xx = 0; xx < 16; ++xx) {
                unsigned cx = __hip_atomic_load(&ctrl[40 + xx], __ATOMIC_RELAXED,
                                                __HIP_MEMORY_SCOPE_AGENT);
                if (cx >= 32u) { win = xx; break; }
            }
            __hip_atomic_store(&ctrl[61], win, __ATOMIC_RELAXED,
                               __HIP_MEMORY_SCOPE_AGENT);
        }
        unsigned win;
        do {
            win = __hip_atomic_load(&ctrl[61], __ATOMIC_RELAXED,
                                    __HIP_MEMORY_SCOPE_AGENT);
        } while (win == 0xffffffffu);
        bool cons = (win == xcc && myidx < 32u);
        s_chunk = cons ? (int)myidx : -1;
        s_pid = cons ? -1
                     : (int)__hip_atomic_fetch_add(&ctrl[62], 1u,
                           __ATOMIC_RELAXED, __HIP_MEMORY_SCOPE_AGENT);
    }
    __syncthreads();
    const int chunk = s_chunk;
    const int w = tid >> 6, lane = tid & 63;
    const int col = lane & 15, quad = lane >> 4;
    unsigned* slowf = ctrl;          // [0..31]  agent / MALL
    unsigned* fastf = ctrl + 64;     // [64..95] plain / XCD L2
    unsigned* done  = ctrl + 256;

    if (chunk < 0) {
        // =================== PRODUCER: xg projection tiles ===================
        const int pid = s_pid;
        for (int g = pid; g < T_SEQ * 64; g += 224) {
            const int t = g >> 6, jt = g & 63;
            const unsigned short* eb = emb_bf + (size_t)t * NB * EPD;
            const unsigned short* wb = wih_bf + (size_t)(jt * 64 + w * 16 + col) * EPD;
            const unsigned short* ea0 = eb + (size_t)col * EPD;
            const unsigned short* ea1 = eb + (size_t)(16 + col) * EPD;

            f32x4 acc0 = {0.f, 0.f, 0.f, 0.f};
            f32x4 acc1 = {0.f, 0.f, 0.f, 0.f};
#pragma unroll
            for (int kc = 0; kc < EPD / 32; ++kc) {
                int ko = kc * 32 + quad * 8;
                s16x8 a0 = *(const s16x8*)&ea0[ko];
                s16x8 a1 = *(const s16x8*)&ea1[ko];
                s16x8 bb = *(const s16x8*)&wb[ko];
                acc0 = __builtin_amdgcn_mfma_f32_16x16x32_bf16(a0, bb, acc0, 0, 0, 0);
                acc1 = __builtin_amdgcn_mfma_f32_16x16x32_bf16(a1, bb, acc1, 0, 0, 0);
            }
            const int jp = jt * 64 + w * 16 + col;
            const float bi = biasg[jp];
            size_t base = ((size_t)t * NJ + jp) * NB;
            union { s16x4 v; u64 q; } p0, p1;
#pragma unroll
            for (int r = 0; r < 4; ++r) {
                p0.v[r] = (short)f2bf(acc0[r] + bi);
                p1.v[r] = (short)f2bf(acc1[r] + bi);
            }
            __hip_atomic_store((u64*)&xg[base + quad * 4], p0.q,
                               __ATOMIC_RELAXED, __HIP_MEMORY_SCOPE_AGENT);
            __hip_atomic_store((u64*)&xg[base + 16 + quad * 4], p1.q,
                               __ATOMIC_RELAXED, __HIP_MEMORY_SCOPE_AGENT);
            __syncthreads();   // stores vmcnt-drained (MALL-ack'd)
            if (tid == 0)
                __hip_atomic_fetch_add(&done[t], 1u, __ATOMIC_RELAXED,
                                       __HIP_MEMORY_SCOPE_AGENT);
        }
        // =================== HEATER: hold DPM clocks up ===================
        float hx = 1.0f + (float)tid;
        for (;;) {
#pragma unroll 16
            for (int i = 0; i < 2048; ++i)
                hx = __builtin_fmaf(hx, 0.9999999f, 1.0e-7f);
            if (__hip_atomic_load(&ctrl[63], __ATOMIC_RELAXED,
                                  __HIP_MEMORY_SCOPE_AGENT) != 0u) break;
        }
        if (hx == 123.456f) *(volatile float*)h_q = hx;   // unreachable sink
        return;
    }

    // ===================== CONSUMER: LSTM recurrence =====================
    const int bh = w >> 1, p = w & 1;
    unsigned* s_w32 = (unsigned*)s_w;

    // ---- stage W_hh -> LDS fp8 x256, XOR-swizzled on 8-B blocks ----
    for (int idx = tid; idx < 128 * 256; idx += 256) {
        int r = idx >> 8, dw = idx & 255;
        int g = r >> 5, uu = r & 31, m = chunk * 32 + uu;
        float4 w4 = make_float4(0.f, 0.f, 0.f, 0.f);
        if (m < NH && dw < 250)
            w4 = *(const float4*)&W_hh[(size_t)(g * NH + m) * NH + dw * 4];
        int p0 = __builtin_amdgcn_cvt_pk_fp8_f32(w4.x * WSCALE, w4.y * WSCALE, 0, false);
        int p1 = __builtin_amdgcn_cvt_pk_fp8_f32(w4.z * WSCALE, w4.w * WSCALE, 0, false);
        unsigned v = ((unsigned)p0 & 0xffffu) | ((unsigned)p1 << 16);
        int kb = dw >> 1;
        int kbs = kb ^ (r & 15);
        s_w32[r * 256 + (kbs << 1) + (dw & 1)] = v;
    }
    // ---- zero own chunk of page 0 (plain store -> local L2) ----
    *(unsigned*)(h_q + (size_t)chunk * 1024 + tid * 4) = 0u;
    __syncthreads();   // vmcnt drained
    if (tid == 0) {
        fastf[chunk] = 1u;                                   // plain -> L2
        __hip_atomic_store(&slowf[chunk], 1u, __ATOMIC_RELAXED,
                           __HIP_MEMORY_SCOPE_AGENT);        // MALL copy
    }

    // ---- gated xg prefetch t=0 ----
    int ready = 0;
    ready = gate_xg(done, ready, 0, lane);
    s16x4 xcur[4];
#pragma unroll
    for (int g = 0; g < 4; ++g)
        xcur[g] = *(const s16x4*)&xg[((size_t)0 * NJ + chunk * 128 + (2 * g + p) * 16 + col) * NB
                                     + bh * 16 + quad * 4];

    float c[4] = {0.f, 0.f, 0.f, 0.f};
    const int rw = quad * 4;
    const int boff = (bh * 16 + col) * 32 + quad * 8;

    for (int t = 0; t < T_SEQ; ++t) {
        // ---- poll page-t flags: nt (L2) fast path, agent every 8th spin ----
        const unsigned need = (unsigned)(t + 1);
        unsigned spins = 0;
        for (;;) {
            unsigned v = need;
            if (lane < 32) {
                if ((spins & 7u) == 7u)
                    v = __hip_atomic_load(&slowf[lane], __ATOMIC_RELAXED,
                                          __HIP_MEMORY_SCOPE_AGENT);
                else
                    v = nt_poll(&fastf[lane]);
            }
            ++spins;
            if (__all((int)(v >= need))) break;
        }
        asm volatile("" ::: "memory");

        // ---- burst load page t (plain, fresh addrs, local L2) ----
        const unsigned char* pb = h_q + (size_t)t * 32768 + boff;
        u64 a[32];
#pragma unroll
        for (int kc = 0; kc < 32; ++kc)
            a[kc] = *(const u64*)(pb + (size_t)kc * 1024);

        f32x4 acc0 = {0.f, 0.f, 0.f, 0.f};
        f32x4 acc1 = {0.f, 0.f, 0.f, 0.f};
        f32x4 acc2 = {0.f, 0.f, 0.f, 0.f};
        f32x4 acc3 = {0.f, 0.f, 0.f, 0.f};
#pragma unroll
        for (int kc = 0; kc < 32; ++kc) {
            int kb = kc * 4 + quad;
            u64 b0 = *(const u64*)&s_w[((0 * 2 + p) * 16 + col) * 1024 + ((kb ^ col) << 3)];
            u64 b1 = *(const u64*)&s_w[((1 * 2 + p) * 16 + col) * 1024 + ((kb ^ col) << 3)];
            u64 b2 = *(const u64*)&s_w[((2 * 2 + p) * 16 + col) * 1024 + ((kb ^ col) << 3)];
            u64 b3 = *(const u64*)&s_w[((3 * 2 + p) * 16 + col) * 1024 + ((kb ^ col) << 3)];
            acc0 = __builtin_amdgcn_mfma_f32_16x16x32_fp8_fp8((long)a[kc], (long)b0, acc0, 0, 0, 0);
            acc1 = __builtin_amdgcn_mfma_f32_16x16x32_fp8_fp8((long)a[kc], (long)b1, acc1, 0, 0, 0);
            acc2 = __builtin_amdgcn_mfma_f32_16x16x32_fp8_fp8((long)a[kc], (long)b2, acc2, 0, 0, 0);
            acc3 = __builtin_amdgcn_mfma_f32_16x16x32_fp8_fp8((long)a[kc], (long)b3, acc3, 0, 0, 0);
        }

        // ---- epilogue: 4 cells; DIRECT byte stores (no LDS bounce) ----
        float hv[4];
#pragma unroll
        for (int r = 0; r < 4; ++r) {
            float gi = acc0[r] * GSCALE + bf2f((unsigned short)xcur[0][r]);
            float gf = acc1[r] * GSCALE + bf2f((unsigned short)xcur[1][r]);
            float gg = acc2[r] * GSCALE + bf2f((unsigned short)xcur[2][r]);
            float go = acc3[r] * GSCALE + bf2f((unsigned short)xcur[3][r]);
            c[r] = fsig(gf) * c[r] + fsig(gi) * ftanh(gg);
            hv[r] = fsig(go) * ftanh(c[r]);
        }
        {
            int p01 = __builtin_amdgcn_cvt_pk_fp8_f32(hv[0] * HSCALE, hv[1] * HSCALE, 0, false);
            int p23 = __builtin_amdgcn_cvt_pk_fp8_f32(hv[2] * HSCALE, hv[3] * HSCALE, 0, false);
            unsigned char* pg = h_q + (size_t)(t + 1) * 32768 + (size_t)chunk * 1024
                              + p * 16 + col;
            pg[(bh * 16 + rw + 0) * 32] = (unsigned char)(p01 & 0xff);
            pg[(bh * 16 + rw + 1) * 32] = (unsigned char)((p01 >> 8) & 0xff);
            pg[(bh * 16 + rw + 2) * 32] = (unsigned char)(p23 & 0xff);
            pg[(bh * 16 + rw + 3) * 32] = (unsigned char)((p23 >> 8) & 0xff);
        }
        __syncthreads();   // per-wave vmcnt drain + barrier: chunk in local L2
        if (tid == 0) {
            fastf[chunk] = (unsigned)(t + 2);                 // plain -> L2
            __hip_atomic_store(&slowf[chunk], (unsigned)(t + 2),
                               __ATOMIC_RELAXED, __HIP_MEMORY_SCOPE_AGENT);
        }

        // ---- off critical path: gated xg prefetch t+1 ----
        if (t + 1 < T_SEQ) {
            ready = gate_xg(done, ready, t + 1, lane);
#pragma unroll
            for (int g = 0; g < 4; ++g)
                xcur[g] = *(const s16x4*)&xg[((size_t)(t + 1) * NJ + chunk * 128 + (2 * g + p) * 16 + col) * NB
                                             + bh * 16 + quad * 4];
        }
    }
    // stop heaters (any consumer finishing is fine; chunk 0 does it)
    if (chunk == 0 && tid == 0)
        __hip_atomic_store(&ctrl[63], 1u, __ATOMIC_RELAXED,
                           __HIP_MEMORY_SCOPE_AGENT);
}

// ---------------------------------------------------------------------------
// tag_gemm (fp8): ts[m][n] = h[m] . lin_w[n]
// ---------------------------------------------------------------------------
__global__ __launch_bounds__(64) void tag_gemm(
    const unsigned char* __restrict__ h_q,
    const unsigned char* __restrict__ linw_q, float* __restrict__ ts)
{
    const int m0 = blockIdx.x * 16, lane = threadIdx.x;
    const int col = lane & 15, quad = lane >> 4;
    const int m = m0 + col, t = m >> 5, b = m & 31;
    const unsigned char* pa = h_q + (size_t)(t + 1) * 32768 + b * 32 + quad * 8;
    const unsigned char* pw = linw_q + (size_t)col * 1024 + quad * 8;

    f32x4 acc = {0.f, 0.f, 0.f, 0.f};
#pragma unroll 8
    for (int kc = 0; kc < 32; ++kc) {
        u64 a  = *(const u64*)(pa + (size_t)kc * 1024);
        u64 bv = *(const u64*)(pw + kc * 32);
        acc = __builtin_amdgcn_mfma_f32_16x16x32_fp8_fp8((long)a, (long)bv, acc, 0, 0, 0);
    }
#pragma unroll
    for (int r = 0; r < 4; ++r)
        ts[(size_t)(m0 + quad * 4 + r) * 16 + col] = acc[r] * TSCALE;
}

// ---------------------------------------------------------------------------
__global__ __launch_bounds__(320) void em_kernel(
    const float* __restrict__ ts, const float* __restrict__ lin_b,
    float* __restrict__ em)
{
    __shared__ float s_ts[NB * NK];
    __shared__ float s_lse[NK];
    const int t = blockIdx.x, tid = threadIdx.x;
    float val = 0.f;
    int b = tid / NK, k = tid - b * NK;
    if (tid < NB * NK) {
        val = ts[(size_t)(t * NB + b) * 16 + k] + lin_b[k];
        s_ts[b * NK + k] = val;
    }
    __syncthreads();
    if (tid < NK) {
        float m = -1e30f;
        for (int bb = 0; bb < NB; ++bb) m = fmaxf(m, s_ts[bb * NK + tid]);
        float s = 0.f;
        for (int bb = 0; bb < NB; ++bb) s += __expf(s_ts[bb * NK + tid] - m);
        s_lse[tid] = m + __logf(s);
    }
    __syncthreads();
    if (tid < NB * NK)
        em[((size_t)t * NB + b) * NK + k] = val - s_lse[k];
}

// ---------------------------------------------------------------------------
__global__ __launch_bounds__(320) void crf_kernel(
    const int* __restrict__ y, const float* __restrict__ em,
    const float* __restrict__ start_trans, const float* __restrict__ end_trans,
    const float* __restrict__ trans, float* __restrict__ out)
{
    __shared__ float s_trans[NK * NK];
    __shared__ float s_alpha[NB * NK];
    __shared__ float s_red[NB];
    const int tid = threadIdx.x;
    if (tid < NK * NK) s_trans[tid] = trans[tid];
    __syncthreads();

    float num = 0.f;
    if (tid < NB) {
        int b = tid, yp = y[b];
        num = start_trans[yp] + em[(size_t)b * NK + yp];
        for (int t = 1; t < T_SEQ; ++t) {
            int yc = y[t * NB + b];
            num += s_trans[yp * NK + yc] + em[((size_t)t * NB + b) * NK + yc];
            yp = yc;
        }
        num += end_trans[yp];
    }

    const int b = tid / NK, k = tid - (tid / NK) * NK;
    if (tid < NB * NK)
        s_alpha[tid] = start_trans[k] + em[(size_t)b * NK + k];
    __syncthreads();

    for (int t = 1; t < T_SEQ; ++t) {
        float nv = 0.f;
        if (tid < NB * NK) {
            float m = -1e30f;
#pragma unroll
            for (int i = 0; i < NK; ++i)
                m = fmaxf(m, s_alpha[b * NK + i] + s_trans[i * NK + k]);
            float s = 0.f;
#pragma unroll
            for (int i = 0; i < NK; ++i)
                s += __expf(s_alpha[b * NK + i] + s_trans[i * NK + k] - m);
            nv = em[((size_t)t * NB + b) * NK + k] + m + __logf(s);
        }
        __syncthreads();
        if (tid < NB * NK) s_alpha[tid] = nv;
        __syncthreads();
    }

    if (tid < NB) {
        float m = -1e30f;
        for (int k2 = 0; k2 < NK; ++k2)
            m = fmaxf(m, s_alpha[tid * NK + k2] + end_trans[k2]);
        float s = 0.f;
        for (int k2 = 0; k2 < NK; ++k2)
            s += __expf(s_alpha[tid * NK + k2] + end_trans[k2] - m);
        s_red[tid] = num - (m + __logf(s));
    }
    __syncthreads();
    if (tid == 0) {
        float tot = 0.f;
        for (int i = 0; i < NB; ++i) tot += s_red[i];
        out[0] = tot;
    }
}

// ---------------------------------------------------------------------------
extern "C" void kernel_launch(void* const* d_in, const int* in_sizes, int n_in,
                              void* d_out, int out_size, void* d_ws, size_t ws_size,
                              hipStream_t stream)
{
    const int*   x           = (const int*)d_in[0];
    const int*   y           = (const int*)d_in[1];
    const float* embed_w     = (const float*)d_in[2];
    const float* W_ih        = (const float*)d_in[3];
    const float* W_hh        = (const float*)d_in[4];
    const float* b_ih        = (const float*)d_in[5];
    const float* b_hh        = (const float*)d_in[6];
    const float* lin_w       = (const float*)d_in[7];
    const float* lin_b       = (const float*)d_in[8];
    const float* start_trans = (const float*)d_in[9];
    const float* end_trans   = (const float*)d_in[10];
    const float* trans       = (const float*)d_in[11];
    float* out = (float*)d_out;

    char* ws = (char*)d_ws;
    unsigned short* xg     = (unsigned short*)(ws);               // 52,428,800 B
    float*          ts     = (float*)(ws);                        // aliases xg (dead post-lstm)
    unsigned char*  h_q    = (unsigned char*)(ws + 52428800);     //  6,586,368 B
    unsigned char*  linw_q = (unsigned char*)(ws + 59015168);     //     16,384 B
    float*          em     = (float*)(ws + 65601536);             //    230,400 B
    unsigned*       ctrl   = (unsigned*)(ws + 65831936);          //      8,192 B
    float*          biasg  = (float*)(ws + 65840128);             //     16,384 B
    unsigned short* emb_bf = (unsigned short*)(ws + 65856512);    //  4,096,000 B
    unsigned short* wih_bf = (unsigned short*)(ws + 69952512);    //  2,621,440 B

    prep_emb<<<dim3(T_SEQ), 256, 0, stream>>>(x, embed_w, emb_bf, ctrl);
    prep_w<<<dim3(64), 256, 0, stream>>>(W_ih, b_ih, b_hh, lin_w, wih_bf, biasg, linw_q);

    lstm_kernel<<<dim3(256), 256, 0, stream>>>(W_hh, emb_bf, wih_bf, biasg,
                                               xg, h_q, ctrl);

    tag_gemm<<<dim3(400), 64, 0, stream>>>(h_q, linw_q, ts);
    em_kernel<<<dim3(T_SEQ), 320, 0, stream>>>(ts, lin_b, em);
    crf_kernel<<<dim3(1), 320, 0, stream>>>(y, em, start_trans, end_trans, trans, out);
}

// Round 13
// 1153.531 us; speedup vs baseline: 19.2981x; 1.1924x over previous
//
#include <hip/hip_runtime.h>

#define T_SEQ 200
#define NB    32
#define NE    300
#define NH    1000
#define NK    9
#define NJ    4096          // xg rows per t
#define EPD   320           // padded embed K
#define WSCALE 256.0f
#define HSCALE 16.0f
#define LSCALE 512.0f
#define GSCALE (1.0f / (256.0f * 16.0f))
#define TSCALE (1.0f / (16.0f * 512.0f))

typedef __attribute__((ext_vector_type(4))) float f32x4;
typedef __attribute__((ext_vector_type(8))) short s16x8;
typedef __attribute__((ext_vector_type(4))) short s16x4;
typedef unsigned long long u64;

__device__ __forceinline__ unsigned short f2bf(float f) {
    union { float f; unsigned u; } v; v.f = f;
    unsigned r = v.u + 0x7FFFu + ((v.u >> 16) & 1u);   // RNE
    return (unsigned short)(r >> 16);
}
__device__ __forceinline__ float bf2f(unsigned short h) {
    union { unsigned u; float f; } v; v.u = ((unsigned)h) << 16;
    return v.f;
}
__device__ __forceinline__ float ftanh(float x) {
    float e = __expf(fminf(2.f * x, 80.f));
    return (e - 1.f) / (e + 1.f);
}
__device__ __forceinline__ float fsig(float x) {
    return 1.f / (1.f + __expf(-x));
}
// non-temporal dword load: no L1 allocate -> served by (XCD) L2
__device__ __forceinline__ unsigned nt_poll(const unsigned* p) {
    unsigned r;
    asm volatile("global_load_dword %0, %1, off nt\n\t"
                 "s_waitcnt vmcnt(0)"
                 : "=v"(r) : "v"(p) : "memory");
    return r;
}
// plain store, compiler-opaque (workgroup-scope relaxed -> global_store_dword)
__device__ __forceinline__ void plain_pub(unsigned* p, unsigned v) {
    __hip_atomic_store(p, v, __ATOMIC_RELAXED, __HIP_MEMORY_SCOPE_WORKGROUP);
}

// ---------------------------------------------------------------------------
// ctrl map: [0..31] slowf (agent/MALL) | [64..95] fastf (plain/L2)
// [40..55] XCD tickets | [60] arrivals | [61] winner | [62] prod ticket
// [63] mode verdict (0=undecided, 1=nt, 2=agent) | [256..455] done[t]
// ---------------------------------------------------------------------------
__global__ __launch_bounds__(256) void prep_emb(
    const int* __restrict__ x, const float* __restrict__ embed_w,
    unsigned short* __restrict__ emb_bf, unsigned* __restrict__ ctrl)
{
    const int t = blockIdx.x, tid = threadIdx.x;
    if (blockIdx.x == 0) {
        for (int i = tid; i < 2048; i += 256)
            ctrl[i] = (i == 61) ? 0xffffffffu : 0u;
    }
    for (int idx = tid; idx < NB * EPD; idx += 256) {
        int b = idx / EPD, e = idx - b * EPD;
        float v = (e < NE) ? embed_w[(size_t)x[t * NB + b] * NE + e] : 0.f;
        emb_bf[((size_t)t * NB + b) * EPD + e] = f2bf(v);
    }
}

// ---------------------------------------------------------------------------
__global__ __launch_bounds__(256) void prep_w(
    const float* __restrict__ W_ih, const float* __restrict__ b_ih,
    const float* __restrict__ b_hh, const float* __restrict__ lin_w,
    unsigned short* __restrict__ wih_bf, float* __restrict__ biasg,
    unsigned char* __restrict__ linw_q)
{
    const int blk = blockIdx.x, tid = threadIdx.x;
    for (int idx = tid; idx < 64 * EPD; idx += 256) {
        int jr = idx / EPD, e = idx - jr * EPD;
        int jp = blk * 64 + jr;
        int wgu = jp >> 7, rr = jp & 127, g = rr >> 5, uu = rr & 31;
        int m = wgu * 32 + uu;
        float v = (m < NH && e < NE) ? W_ih[(size_t)(g * NH + m) * NE + e] : 0.f;
        wih_bf[(size_t)jp * EPD + e] = f2bf(v);
    }
    if (tid < 64) {
        int jp = blk * 64 + tid;
        int wgu = jp >> 7, rr = jp & 127, g = rr >> 5, uu = rr & 31;
        int m = wgu * 32 + uu;
        biasg[jp] = (m < NH) ? (b_ih[g * NH + m] + b_hh[g * NH + m]) : 0.f;
    }
    if (blk < 16) {
        int n = blk, k = tid * 4;
        float v0 = (n < NK && k + 0 < NH) ? lin_w[(size_t)n * NH + k + 0] * LSCALE : 0.f;
        float v1 = (n < NK && k + 1 < NH) ? lin_w[(size_t)n * NH + k + 1] * LSCALE : 0.f;
        float v2 = (n < NK && k + 2 < NH) ? lin_w[(size_t)n * NH + k + 2] * LSCALE : 0.f;
        float v3 = (n < NK && k + 3 < NH) ? lin_w[(size_t)n * NH + k + 3] * LSCALE : 0.f;
        int p01 = __builtin_amdgcn_cvt_pk_fp8_f32(v0, v1, 0, false);
        int p23 = __builtin_amdgcn_cvt_pk_fp8_f32(v2, v3, 0, false);
        ((unsigned*)linw_q)[n * 256 + tid] =
            ((unsigned)p01 & 0xffffu) | ((unsigned)p23 << 16);
    }
}

// ---------------------------------------------------------------------------
__device__ __forceinline__ int gate_xg(unsigned* done, int ready, int tn, int lane) {
    while (ready <= tn) {
        unsigned v = 64u;
        if (lane < 8 && ready + lane < T_SEQ)
            v = __hip_atomic_load(&done[ready + lane], __ATOMIC_RELAXED,
                                  __HIP_MEMORY_SCOPE_AGENT);
        unsigned m = (unsigned)__ballot((int)(v >= 64u)) & 255u;
        if (m & 1u) {
            unsigned run = (m == 255u) ? 8u : (unsigned)__builtin_ctz(~m);
            ready += (int)run;
        } else {
            __builtin_amdgcn_s_sleep(1);
        }
    }
    return ready;
}

// ---------------------------------------------------------------------------
// mega kernel: grid 256, 1 WG/CU. Winner XCD's 32 WGs = consumers; other 224
// = producers (xg tiles) then exit. Flag transport chosen at runtime by a
// startup nt-visibility self-test (chunk 0 decides, ctrl[63] broadcasts):
// mode 1: plain publish -> XCD L2, nt poll (no MALL ops near the poll)
// mode 2: R9-proven agent publish/poll (MALL)
// ---------------------------------------------------------------------------
__global__ __launch_bounds__(256, 1) void lstm_kernel(
    const float* __restrict__ W_hh,
    const unsigned short* __restrict__ emb_bf,
    const unsigned short* __restrict__ wih_bf,
    const float* __restrict__ biasg,
    unsigned short* __restrict__ xg,
    unsigned char* __restrict__ h_q,
    unsigned* __restrict__ ctrl)
{
    __shared__ __align__(16) unsigned char s_w[128 * 1024];   // 131,072 B
    __shared__ int s_chunk, s_pid, s_mode;

    const int tid = threadIdx.x;

    // ---- election (startup only, MALL atomics; R9-proven) ----
    if (tid == 0) {
        unsigned xcc;
        asm volatile("s_getreg_b32 %0, hwreg(HW_REG_XCC_ID)" : "=s"(xcc));
        xcc &= 15u;
        unsigned myidx = __hip_atomic_fetch_add(&ctrl[40 + xcc], 1u,
                             __ATOMIC_RELAXED, __HIP_MEMORY_SCOPE_AGENT);
        __threadfence();
        unsigned tot = __hip_atomic_fetch_add(&ctrl[60], 1u,
                             __ATOMIC_RELAXED, __HIP_MEMORY_SCOPE_AGENT);
        if (tot == 255u) {
            __threadfence();
            unsigned win = 0u;
            for (unsigned xx = 0; xx < 16; ++xx) {
                unsigned cx = __hip_atomic_load(&ctrl[40 + xx], __ATOMIC_RELAXED,
                                                __HIP_MEMORY_SCOPE_AGENT);
                if (cx >= 32u) { win = xx; break; }
            }
            __hip_atomic_store(&ctrl[61], win, __ATOMIC_RELAXED,
                               __HIP_MEMORY_SCOPE_AGENT);
        }
        unsigned win;
        do {
            win = __hip_atomic_load(&ctrl[61], __ATOMIC_RELAXED,
                                    __HIP_MEMORY_SCOPE_AGENT);
        } while (win == 0xffffffffu);
        bool cons = (win == xcc && myidx < 32u);
        s_chunk = cons ? (int)myidx : -1;
        s_pid = cons ? -1
                     : (int)__hip_atomic_fetch_add(&ctrl[62], 1u,
                           __ATOMIC_RELAXED, __HIP_MEMORY_SCOPE_AGENT);
    }
    __syncthreads();
    const int chunk = s_chunk;
    const int w = tid >> 6, lane = tid & 63;
    const int col = lane & 15, quad = lane >> 4;
    unsigned* slowf = ctrl;          // [0..31]  agent / MALL
    unsigned* fastf = ctrl + 64;     // [64..95] plain / XCD L2
    unsigned* done  = ctrl + 256;

    if (chunk < 0) {
        // =================== PRODUCER: xg projection tiles ===================
        const int pid = s_pid;
        for (int g = pid; g < T_SEQ * 64; g += 224) {
            const int t = g >> 6, jt = g & 63;
            const unsigned short* eb = emb_bf + (size_t)t * NB * EPD;
            const unsigned short* wb = wih_bf + (size_t)(jt * 64 + w * 16 + col) * EPD;
            const unsigned short* ea0 = eb + (size_t)col * EPD;
            const unsigned short* ea1 = eb + (size_t)(16 + col) * EPD;

            f32x4 acc0 = {0.f, 0.f, 0.f, 0.f};
            f32x4 acc1 = {0.f, 0.f, 0.f, 0.f};
#pragma unroll
            for (int kc = 0; kc < EPD / 32; ++kc) {
                int ko = kc * 32 + quad * 8;
                s16x8 a0 = *(const s16x8*)&ea0[ko];
                s16x8 a1 = *(const s16x8*)&ea1[ko];
                s16x8 bb = *(const s16x8*)&wb[ko];
                acc0 = __builtin_amdgcn_mfma_f32_16x16x32_bf16(a0, bb, acc0, 0, 0, 0);
                acc1 = __builtin_amdgcn_mfma_f32_16x16x32_bf16(a1, bb, acc1, 0, 0, 0);
            }
            const int jp = jt * 64 + w * 16 + col;
            const float bi = biasg[jp];
            size_t base = ((size_t)t * NJ + jp) * NB;
            union { s16x4 v; u64 q; } p0, p1;
#pragma unroll
            for (int r = 0; r < 4; ++r) {
                p0.v[r] = (short)f2bf(acc0[r] + bi);
                p1.v[r] = (short)f2bf(acc1[r] + bi);
            }
            __hip_atomic_store((u64*)&xg[base + quad * 4], p0.q,
                               __ATOMIC_RELAXED, __HIP_MEMORY_SCOPE_AGENT);
            __hip_atomic_store((u64*)&xg[base + 16 + quad * 4], p1.q,
                               __ATOMIC_RELAXED, __HIP_MEMORY_SCOPE_AGENT);
            __syncthreads();   // stores vmcnt-drained (MALL-ack'd)
            if (tid == 0)
                __hip_atomic_fetch_add(&done[t], 1u, __ATOMIC_RELAXED,
                                       __HIP_MEMORY_SCOPE_AGENT);
        }
        return;
    }

    // ===================== CONSUMER: LSTM recurrence =====================
    const int bh = w >> 1, p = w & 1;
    unsigned* s_w32 = (unsigned*)s_w;

    // ---- stage W_hh -> LDS fp8 x256, XOR-swizzled on 8-B blocks ----
    for (int idx = tid; idx < 128 * 256; idx += 256) {
        int r = idx >> 8, dw = idx & 255;
        int g = r >> 5, uu = r & 31, m = chunk * 32 + uu;
        float4 w4 = make_float4(0.f, 0.f, 0.f, 0.f);
        if (m < NH && dw < 250)
            w4 = *(const float4*)&W_hh[(size_t)(g * NH + m) * NH + dw * 4];
        int p0 = __builtin_amdgcn_cvt_pk_fp8_f32(w4.x * WSCALE, w4.y * WSCALE, 0, false);
        int p1 = __builtin_amdgcn_cvt_pk_fp8_f32(w4.z * WSCALE, w4.w * WSCALE, 0, false);
        unsigned v = ((unsigned)p0 & 0xffffu) | ((unsigned)p1 << 16);
        int kb = dw >> 1;
        int kbs = kb ^ (r & 15);
        s_w32[r * 256 + (kbs << 1) + (dw & 1)] = v;
    }
    // ---- zero own chunk of page 0 (plain store -> local L2) ----
    *(unsigned*)(h_q + (size_t)chunk * 1024 + tid * 4) = 0u;
    __syncthreads();   // vmcnt drained
    if (tid == 0) {
        plain_pub(&fastf[chunk], 1u);
        __hip_atomic_store(&slowf[chunk], 1u, __ATOMIC_RELAXED,
                           __HIP_MEMORY_SCOPE_AGENT);
    }
    // ---- nt-visibility self-test; chunk 0 decides, ctrl[63] broadcasts ----
    if (chunk == 0) {
        if (tid < 64) {
            int mode = 2;
            for (int it = 0; it < 8192; ++it) {
                unsigned v = (lane < 32) ? nt_poll(&fastf[lane]) : 1u;
                if (__all((int)(v >= 1u))) { mode = 1; break; }
            }
            if (tid == 0) {
                __hip_atomic_store(&ctrl[63], (unsigned)mode, __ATOMIC_RELAXED,
                                   __HIP_MEMORY_SCOPE_AGENT);
                s_mode = mode;
            }
        }
    } else {
        if (tid == 0) {
            unsigned m;
            do {
                m = __hip_atomic_load(&ctrl[63], __ATOMIC_RELAXED,
                                      __HIP_MEMORY_SCOPE_AGENT);
            } while (m == 0u);
            s_mode = (int)m;
        }
    }
    __syncthreads();
    const int mode = s_mode;

    // ---- gated xg load t=0 ----
    int ready = 0;
    ready = gate_xg(done, ready, 0, lane);
    s16x4 xcur[4], xnxt[4];
#pragma unroll
    for (int g = 0; g < 4; ++g)
        xcur[g] = *(const s16x4*)&xg[((size_t)0 * NJ + chunk * 128 + (2 * g + p) * 16 + col) * NB
                                     + bh * 16 + quad * 4];

    float c[4] = {0.f, 0.f, 0.f, 0.f};
    const int rw = quad * 4;
    const int boff = (bh * 16 + col) * 32 + quad * 8;

    for (int t = 0; t < T_SEQ; ++t) {
        // ---- poll page-t flags ----
        const unsigned need = (unsigned)(t + 1);
        if (mode == 1) {
            for (;;) {
                unsigned v = (lane < 32) ? nt_poll(&fastf[lane]) : need;
                if (__all((int)(v >= need))) break;
            }
        } else {
            for (;;) {
                unsigned v = (lane < 32)
                    ? __hip_atomic_load(&slowf[lane], __ATOMIC_RELAXED,
                                        __HIP_MEMORY_SCOPE_AGENT)
                    : need;
                if (__all((int)(v >= need))) break;
            }
        }
        asm volatile("" ::: "memory");

        // ---- burst load page t (plain, fresh addrs, local L2) ----
        const unsigned char* pb = h_q + (size_t)t * 32768 + boff;
        u64 a[32];
#pragma unroll
        for (int kc = 0; kc < 32; ++kc)
            a[kc] = *(const u64*)(pb + (size_t)kc * 1024);

        // ---- gated xg prefetch t+1 (MALL; retires under MFMA+epilogue) ----
        if (t + 1 < T_SEQ) {
            ready = gate_xg(done, ready, t + 1, lane);
#pragma unroll
            for (int g = 0; g < 4; ++g)
                xnxt[g] = *(const s16x4*)&xg[((size_t)(t + 1) * NJ + chunk * 128 + (2 * g + p) * 16 + col) * NB
                                             + bh * 16 + quad * 4];
        }

        f32x4 acc0 = {0.f, 0.f, 0.f, 0.f};
        f32x4 acc1 = {0.f, 0.f, 0.f, 0.f};
        f32x4 acc2 = {0.f, 0.f, 0.f, 0.f};
        f32x4 acc3 = {0.f, 0.f, 0.f, 0.f};
#pragma unroll
        for (int kc = 0; kc < 32; ++kc) {
            int kb = kc * 4 + quad;
            u64 b0 = *(const u64*)&s_w[((0 * 2 + p) * 16 + col) * 1024 + ((kb ^ col) << 3)];
            u64 b1 = *(const u64*)&s_w[((1 * 2 + p) * 16 + col) * 1024 + ((kb ^ col) << 3)];
            u64 b2 = *(const u64*)&s_w[((2 * 2 + p) * 16 + col) * 1024 + ((kb ^ col) << 3)];
            u64 b3 = *(const u64*)&s_w[((3 * 2 + p) * 16 + col) * 1024 + ((kb ^ col) << 3)];
            acc0 = __builtin_amdgcn_mfma_f32_16x16x32_fp8_fp8((long)a[kc], (long)b0, acc0, 0, 0, 0);
            acc1 = __builtin_amdgcn_mfma_f32_16x16x32_fp8_fp8((long)a[kc], (long)b1, acc1, 0, 0, 0);
            acc2 = __builtin_amdgcn_mfma_f32_16x16x32_fp8_fp8((long)a[kc], (long)b2, acc2, 0, 0, 0);
            acc3 = __builtin_amdgcn_mfma_f32_16x16x32_fp8_fp8((long)a[kc], (long)b3, acc3, 0, 0, 0);
        }

        // ---- epilogue: 4 cells; direct byte stores ----
        float hv[4];
#pragma unroll
        for (int r = 0; r < 4; ++r) {
            float gi = acc0[r] * GSCALE + bf2f((unsigned short)xcur[0][r]);
            float gf = acc1[r] * GSCALE + bf2f((unsigned short)xcur[1][r]);
            float gg = acc2[r] * GSCALE + bf2f((unsigned short)xcur[2][r]);
            float go = acc3[r] * GSCALE + bf2f((unsigned short)xcur[3][r]);
            c[r] = fsig(gf) * c[r] + fsig(gi) * ftanh(gg);
            hv[r] = fsig(go) * ftanh(c[r]);
        }
        {
            int p01 = __builtin_amdgcn_cvt_pk_fp8_f32(hv[0] * HSCALE, hv[1] * HSCALE, 0, false);
            int p23 = __builtin_amdgcn_cvt_pk_fp8_f32(hv[2] * HSCALE, hv[3] * HSCALE, 0, false);
            unsigned char* pg = h_q + (size_t)(t + 1) * 32768 + (size_t)chunk * 1024
                              + p * 16 + col;
            pg[(bh * 16 + rw + 0) * 32] = (unsigned char)(p01 & 0xff);
            pg[(bh * 16 + rw + 1) * 32] = (unsigned char)((p01 >> 8) & 0xff);
            pg[(bh * 16 + rw + 2) * 32] = (unsigned char)(p23 & 0xff);
            pg[(bh * 16 + rw + 3) * 32] = (unsigned char)((p23 >> 8) & 0xff);
        }
        __syncthreads();   // vmcnt drain + barrier: chunk in local L2
        if (tid == 0) {
            plain_pub(&fastf[chunk], (unsigned)(t + 2));
            if (mode == 2)
                __hip_atomic_store(&slowf[chunk], (unsigned)(t + 2),
                                   __ATOMIC_RELAXED, __HIP_MEMORY_SCOPE_AGENT);
        }
#pragma unroll
        for (int g = 0; g < 4; ++g) xcur[g] = xnxt[g];
    }
}

// ---------------------------------------------------------------------------
// tag_gemm (fp8): ts[m][n] = h[m] . lin_w[n]
// ---------------------------------------------------------------------------
__global__ __launch_bounds__(64) void tag_gemm(
    const unsigned char* __restrict__ h_q,
    const unsigned char* __restrict__ linw_q, float* __restrict__ ts)
{
    const int m0 = blockIdx.x * 16, lane = threadIdx.x;
    const int col = lane & 15, quad = lane >> 4;
    const int m = m0 + col, t = m >> 5, b = m & 31;
    const unsigned char* pa = h_q + (size_t)(t + 1) * 32768 + b * 32 + quad * 8;
    const unsigned char* pw = linw_q + (size_t)col * 1024 + quad * 8;

    f32x4 acc = {0.f, 0.f, 0.f, 0.f};
#pragma unroll 8
    for (int kc = 0; kc < 32; ++kc) {
        u64 a  = *(const u64*)(pa + (size_t)kc * 1024);
        u64 bv = *(const u64*)(pw + kc * 32);
        acc = __builtin_amdgcn_mfma_f32_16x16x32_fp8_fp8((long)a, (long)bv, acc, 0, 0, 0);
    }
#pragma unroll
    for (int r = 0; r < 4; ++r)
        ts[(size_t)(m0 + quad * 4 + r) * 16 + col] = acc[r] * TSCALE;
}

// ---------------------------------------------------------------------------
__global__ __launch_bounds__(320) void em_kernel(
    const float* __restrict__ ts, const float* __restrict__ lin_b,
    float* __restrict__ em)
{
    __shared__ float s_ts[NB * NK];
    __shared__ float s_lse[NK];
    const int t = blockIdx.x, tid = threadIdx.x;
    float val = 0.f;
    int b = tid / NK, k = tid - b * NK;
    if (tid < NB * NK) {
        val = ts[(size_t)(t * NB + b) * 16 + k] + lin_b[k];
        s_ts[b * NK + k] = val;
    }
    __syncthreads();
    if (tid < NK) {
        float m = -1e30f;
        for (int bb = 0; bb < NB; ++bb) m = fmaxf(m, s_ts[bb * NK + tid]);
        float s = 0.f;
        for (int bb = 0; bb < NB; ++bb) s += __expf(s_ts[bb * NK + tid] - m);
        s_lse[tid] = m + __logf(s);
    }
    __syncthreads();
    if (tid < NB * NK)
        em[((size_t)t * NB + b) * NK + k] = val - s_lse[k];
}

// ---------------------------------------------------------------------------
__global__ __launch_bounds__(320) void crf_kernel(
    const int* __restrict__ y, const float* __restrict__ em,
    const float* __restrict__ start_trans, const float* __restrict__ end_trans,
    const float* __restrict__ trans, float* __restrict__ out)
{
    __shared__ float s_trans[NK * NK];
    __shared__ float s_alpha[NB * NK];
    __shared__ float s_red[NB];
    const int tid = threadIdx.x;
    if (tid < NK * NK) s_trans[tid] = trans[tid];
    __syncthreads();

    float num = 0.f;
    if (tid < NB) {
        int b = tid, yp = y[b];
        num = start_trans[yp] + em[(size_t)b * NK + yp];
        for (int t = 1; t < T_SEQ; ++t) {
            int yc = y[t * NB + b];
            num += s_trans[yp * NK + yc] + em[((size_t)t * NB + b) * NK + yc];
            yp = yc;
        }
        num += end_trans[yp];
    }

    const int b = tid / NK, k = tid - (tid / NK) * NK;
    if (tid < NB * NK)
        s_alpha[tid] = start_trans[k] + em[(size_t)b * NK + k];
    __syncthreads();

    for (int t = 1; t < T_SEQ; ++t) {
        float nv = 0.f;
        if (tid < NB * NK) {
            float m = -1e30f;
#pragma unroll
            for (int i = 0; i < NK; ++i)
                m = fmaxf(m, s_alpha[b * NK + i] + s_trans[i * NK + k]);
            float s = 0.f;
#pragma unroll
            for (int i = 0; i < NK; ++i)
                s += __expf(s_alpha[b * NK + i] + s_trans[i * NK + k] - m);
            nv = em[((size_t)t * NB + b) * NK + k] + m + __logf(s);
        }
        __syncthreads();
        if (tid < NB * NK) s_alpha[tid] = nv;
        __syncthreads();
    }

    if (tid < NB) {
        float m = -1e30f;
        for (int k2 = 0; k2 < NK; ++k2)
            m = fmaxf(m, s_alpha[tid * NK + k2] + end_trans[k2]);
        float s = 0.f;
        for (int k2 = 0; k2 < NK; ++k2)
            s += __expf(s_alpha[tid * NK + k2] + end_trans[k2] - m);
        s_red[tid] = num - (m + __logf(s));
    }
    __syncthreads();
    if (tid == 0) {
        float tot = 0.f;
        for (int i = 0; i < NB; ++i) tot += s_red[i];
        out[0] = tot;
    }
}

// ---------------------------------------------------------------------------
extern "C" void kernel_launch(void* const* d_in, const int* in_sizes, int n_in,
                              void* d_out, int out_size, void* d_ws, size_t ws_size,
                              hipStream_t stream)
{
    const int*   x           = (const int*)d_in[0];
    const int*   y           = (const int*)d_in[1];
    const float* embed_w     = (const float*)d_in[2];
    const float* W_ih        = (const float*)d_in[3];
    const float* W_hh        = (const float*)d_in[4];
    const float* b_ih        = (const float*)d_in[5];
    const float* b_hh        = (const float*)d_in[6];
    const float* lin_w       = (const float*)d_in[7];
    const float* lin_b       = (const float*)d_in[8];
    const float* start_trans = (const float*)d_in[9];
    const float* end_trans   = (const float*)d_in[10];
    const float* trans       = (const float*)d_in[11];
    float* out = (float*)d_out;

    char* ws = (char*)d_ws;
    unsigned short* xg     = (unsigned short*)(ws);               // 52,428,800 B
    float*          ts     = (float*)(ws);                        // aliases xg (dead post-lstm)
    unsigned char*  h_q    = (unsigned char*)(ws + 52428800);     //  6,586,368 B
    unsigned char*  linw_q = (unsigned char*)(ws + 59015168);     //     16,384 B
    float*          em     = (float*)(ws + 65601536);             //    230,400 B
    unsigned*       ctrl   = (unsigned*)(ws + 65831936);          //      8,192 B
    float*          biasg  = (float*)(ws + 65840128);             //     16,384 B
    unsigned short* emb_bf = (unsigned short*)(ws + 65856512);    //  4,096,000 B
    unsigned short* wih_bf = (unsigned short*)(ws + 69952512);    //  2,621,440 B

    prep_emb<<<dim3(T_SEQ), 256, 0, stream>>>(x, embed_w, emb_bf, ctrl);
    prep_w<<<dim3(64), 256, 0, stream>>>(W_ih, b_ih, b_hh, lin_w, wih_bf, biasg, linw_q);

    lstm_kernel<<<dim3(256), 256, 0, stream>>>(W_hh, emb_bf, wih_bf, biasg,
                                               xg, h_q, ctrl);

    tag_gemm<<<dim3(400), 64, 0, stream>>>(h_q, linw_q, ts);
    em_kernel<<<dim3(T_SEQ), 320, 0, stream>>>(ts, lin_b, em);
    crf_kernel<<<dim3(1), 320, 0, stream>>>(y, em, start_trans, end_trans, trans, out);
}